// Round 1
// baseline (3127.903 us; speedup 1.0000x reference)
//
#include <hip/hip_runtime.h>
#include <cstdint>
#include <cstddef>
#include <math.h>

#define NN   4096
#define DD   256
#define E0S  131072
#define NE   (E0S + NN)     // 135168 edges incl. self loops
#define KK   2048
#define NEG_SLOPE 0.2f

// edge accessors: e < E0S -> from input arrays; else self-loop (e - E0S)
__device__ __forceinline__ int esrc(const int* s, int e){ return e < E0S ? s[e] : e - E0S; }
__device__ __forceinline__ int edst(const int* d, int e){ return e < E0S ? d[e] : e - E0S; }

// ---------------- init: zero degree arrays, colmap=-1, zero A_c ----------------
__global__ void init_kernel(int* deg_dst, int* deg_src, int* colmap, float* Ac){
    int i = blockIdx.x * blockDim.x + threadIdx.x;
    int stride = gridDim.x * blockDim.x;
    for (size_t t = i; t < (size_t)KK * KK; t += stride) Ac[t] = 0.f;
    for (int t = i; t < NN; t += stride){ deg_dst[t] = 0; deg_src[t] = 0; colmap[t] = -1; }
}

// ---------------- degree count ----------------
__global__ void count_kernel(const int* e_src, const int* e_dst, int* deg_dst, int* deg_src){
    int e = blockIdx.x * blockDim.x + threadIdx.x;
    if (e < NE){
        atomicAdd(&deg_dst[edst(e_dst, e)], 1);
        atomicAdd(&deg_src[esrc(e_src, e)], 1);
    }
}

// ---------------- exclusive scan of degrees (one block per array) ----------------
__global__ void __launch_bounds__(1024) scan_kernel(const int* degA, int* offA, int* curA,
                                                    const int* degB, int* offB, int* curB){
    const int* deg = (blockIdx.x == 0) ? degA : degB;
    int* off = (blockIdx.x == 0) ? offA : offB;
    int* cur = (blockIdx.x == 0) ? curA : curB;
    __shared__ int part[1024];
    int t = threadIdx.x;
    int base = t * 4;
    int s0 = deg[base], s1 = deg[base+1], s2 = deg[base+2], s3 = deg[base+3];
    int tot = s0 + s1 + s2 + s3;
    part[t] = tot;
    __syncthreads();
    for (int d = 1; d < 1024; d <<= 1){
        int v = (t >= d) ? part[t - d] : 0;
        __syncthreads();
        part[t] += v;
        __syncthreads();
    }
    int excl = part[t] - tot;
    off[base]   = excl;            cur[base]   = excl;
    off[base+1] = excl + s0;       cur[base+1] = excl + s0;
    off[base+2] = excl + s0 + s1;  cur[base+2] = excl + s0 + s1;
    off[base+3] = excl + s0 + s1 + s2; cur[base+3] = excl + s0 + s1 + s2;
    if (t == 1023) off[NN] = part[1023];
}

// ---------------- CSR fill ----------------
__global__ void fill_kernel(const int* e_src, const int* e_dst, int* cur_dst, int* cur_src,
                            int* eid_dst, int* eid_src){
    int e = blockIdx.x * blockDim.x + threadIdx.x;
    if (e < NE){
        int p = atomicAdd(&cur_dst[edst(e_dst, e)], 1); eid_dst[p] = e;
        int q = atomicAdd(&cur_src[esrc(e_src, e)], 1); eid_src[q] = e;
    }
}

// ---------------- sort each CSR segment (determinism) ----------------
__global__ void segsort_kernel(const int* off_dst, int* eid_dst, const int* off_src, int* eid_src){
    int n = blockIdx.x * blockDim.x + threadIdx.x;
    const int* off; int* eid;
    if (n < NN){ off = off_dst; eid = eid_dst; }
    else if (n < 2 * NN){ off = off_src; eid = eid_src; n -= NN; }
    else return;
    int lo = off[n], hi = off[n+1];
    for (int i = lo + 1; i < hi; ++i){
        int v = eid[i]; int j = i - 1;
        while (j >= lo && eid[j] > v){ eid[j+1] = eid[j]; --j; }
        eid[j+1] = v;
    }
}

// ---------------- x_q = segment_max(x[src], dst) : one block per node ----------------
__global__ void segmax_kernel(const float* x, const int* off, const int* eid, const int* e_src,
                              float* x_q){
    int n = blockIdx.x, d = threadIdx.x;
    int lo = off[n], hi = off[n+1];
    float m = -INFINITY;
    for (int t = lo; t < hi; ++t){
        int e = eid[t];
        int s = esrc(e_src, e);
        m = fmaxf(m, x[(size_t)s * DD + d]);
    }
    x_q[(size_t)n * DD + d] = m;
}

// ---------------- x_q_lin = x_q @ lin_w + lin_b ----------------
#define LROWS 8
__global__ void lin_kernel(const float* x_q, const float* w, const float* b, float* out){
    __shared__ float xs[LROWS][DD];
    int col = threadIdx.x;
    int r0 = blockIdx.x * LROWS;
    for (int r = 0; r < LROWS; ++r) xs[r][col] = x_q[(size_t)(r0 + r) * DD + col];
    __syncthreads();
    float acc[LROWS];
    float bc = b[col];
    #pragma unroll
    for (int r = 0; r < LROWS; ++r) acc[r] = bc;
    for (int kk = 0; kk < DD; ++kk){
        float wv = w[(size_t)kk * DD + col];
        #pragma unroll
        for (int r = 0; r < LROWS; ++r) acc[r] = fmaf(xs[r][kk], wv, acc[r]);
    }
    for (int r = 0; r < LROWS; ++r) out[(size_t)(r0 + r) * DD + col] = acc[r];
}

// ---------------- per-node attention dots: q_s = x_q_lin . att_w[0:D], p_s = x . att_w[D:2D] ----
__global__ void nodedots_kernel(const float* x, const float* x_q_lin, const float* att_w,
                                float* q_s, float* p_s){
    int n = blockIdx.x, t = threadIdx.x;
    float v1 = x_q_lin[(size_t)n * DD + t] * att_w[t];
    float v2 = x[(size_t)n * DD + t] * att_w[DD + t];
    __shared__ float s1[256], s2[256];
    s1[t] = v1; s2[t] = v2;
    __syncthreads();
    for (int d = 128; d > 0; d >>= 1){
        if (t < d){ s1[t] += s1[t + d]; s2[t] += s2[t + d]; }
        __syncthreads();
    }
    if (t == 0){ q_s[n] = s1[0]; p_s[n] = s2[0]; }
}

// ---------------- per-dst segment softmax of leaky_relu scores (one wave per node) --------
__global__ void softmax_kernel(const int* off, const int* eid, const int* e_src,
                               const float* q_s, const float* p_s, const float* att_b,
                               float* sc){
    int wave = threadIdx.x >> 6;
    int lane = threadIdx.x & 63;
    int n = blockIdx.x * 4 + wave;
    int lo = off[n], hi = off[n+1];
    float ab = att_b[0];
    float qn = q_s[n];
    float m = -INFINITY;
    for (int t = lo + lane; t < hi; t += 64){
        int e = eid[t];
        float s = qn + p_s[esrc(e_src, e)] + ab;
        s = (s > 0.f) ? s : NEG_SLOPE * s;
        m = fmaxf(m, s);
    }
    #pragma unroll
    for (int d = 32; d > 0; d >>= 1) m = fmaxf(m, __shfl_xor(m, d));
    float sum = 0.f;
    for (int t = lo + lane; t < hi; t += 64){
        int e = eid[t];
        float s = qn + p_s[esrc(e_src, e)] + ab;
        s = (s > 0.f) ? s : NEG_SLOPE * s;
        float ex = expf(s - m);
        sc[e] = ex;
        sum += ex;
    }
    #pragma unroll
    for (int d = 32; d > 0; d >>= 1) sum += __shfl_xor(sum, d);
    float inv = 1.f / sum;
    for (int t = lo + lane; t < hi; t += 64){
        sc[eid[t]] *= inv;
    }
}

// ---------------- xn = segment_sum(x[src] * sc, dst) : one block per node ----------------
__global__ void xn_kernel(const float* x, const int* off, const int* eid, const int* e_src,
                          const float* sc, float* xn){
    int n = blockIdx.x, d = threadIdx.x;
    int lo = off[n], hi = off[n+1];
    float acc = 0.f;
    for (int t = lo; t < hi; ++t){
        int e = eid[t];
        acc = fmaf(sc[e], x[(size_t)esrc(e_src, e) * DD + d], acc);
    }
    xn[(size_t)n * DD + d] = acc;
}

// ---------------- LEConv dots ----------------
__global__ void fitdots_kernel(const float* xn, const float* le1_w, const float* le1_b,
                               const float* le2_w, const float* le3_w, const float* le3_b,
                               float* a_, float* b_, float* c_){
    int n = blockIdx.x, t = threadIdx.x;
    float xv = xn[(size_t)n * DD + t];
    __shared__ float s1[256], s2[256], s3[256];
    s1[t] = xv * le1_w[t];
    s2[t] = xv * le2_w[t];
    s3[t] = xv * le3_w[t];
    __syncthreads();
    for (int d = 128; d > 0; d >>= 1){
        if (t < d){ s1[t] += s1[t+d]; s2[t] += s2[t+d]; s3[t] += s3[t+d]; }
        __syncthreads();
    }
    if (t == 0){
        a_[n] = s1[0] + le1_b[0];
        b_[n] = s2[0];
        c_[n] = s3[0] + le3_b[0];
    }
}

// ---------------- fitness = sigmoid(segsum(a[src]-b[dst]) + c) (one wave per node) --------
__global__ void fitness_kernel(const int* off, const int* eid, const int* e_src,
                               const float* a_, const float* b_, const float* c_,
                               float* fit){
    int wave = threadIdx.x >> 6;
    int lane = threadIdx.x & 63;
    int n = blockIdx.x * 4 + wave;
    int lo = off[n], hi = off[n+1];
    float bn = b_[n];
    float s = 0.f;
    for (int t = lo + lane; t < hi; t += 64){
        int e = eid[t];
        s += a_[esrc(e_src, e)] - bn;
    }
    #pragma unroll
    for (int d = 32; d > 0; d >>= 1) s += __shfl_xor(s, d);
    if (lane == 0){
        float z = s + c_[n];
        fit[n] = 1.f / (1.f + expf(-z));
    }
}

// ---------------- top-k via bitonic sort of (value desc, idx asc) keys ----------------
__global__ void __launch_bounds__(1024) topk_kernel(const float* fit, int* perm, int* colmap,
                                                    float* out_perm){
    __shared__ unsigned long long keys[NN];
    int t = threadIdx.x;
    for (int i = t; i < NN; i += 1024){
        unsigned int u = __float_as_uint(fit[i]);
        u = (u & 0x80000000u) ? ~u : (u | 0x80000000u);  // monotone map
        u = ~u;                                           // descending
        keys[i] = ((unsigned long long)u << 32) | (unsigned int)i;
    }
    __syncthreads();
    for (unsigned int ssize = 2; ssize <= NN; ssize <<= 1){
        for (unsigned int stride = ssize >> 1; stride > 0; stride >>= 1){
            for (int i = t; i < NN / 2; i += 1024){
                unsigned int idx = 2u * i - (i & (stride - 1u));
                unsigned int par = idx + stride;
                bool asc = ((idx & ssize) == 0u);
                unsigned long long a = keys[idx], b = keys[par];
                if ((a > b) == asc){ keys[idx] = b; keys[par] = a; }
            }
            __syncthreads();
        }
    }
    for (int i = t; i < KK; i += 1024){
        int node = (int)(keys[i] & 0xFFFFFFFFull);
        perm[i] = node;
        colmap[node] = i;
        out_perm[i] = (float)node;
    }
}

// ---------------- x_out = xn[perm] * fitness[perm] ----------------
__global__ void xout_kernel(const float* xn, const float* fit, const int* perm, float* x_out){
    int r = blockIdx.x, d = threadIdx.x;
    int p = perm[r];
    x_out[(size_t)r * DD + d] = xn[(size_t)p * DD + d] * fit[p];
}

// ---------------- colc[e] = colmap[dst(e)] ----------------
__global__ void colc_kernel(const int* e_dst, const int* colmap, int* colc){
    int e = blockIdx.x * blockDim.x + threadIdx.x;
    if (e < NE) colc[e] = colmap[edst(e_dst, e)];
}

// ---------------- A_c += sum over edges e1=(i,j): outer(Sp[i,:], Sp[j,:]) * w ------------
__global__ void ac_kernel(const int* e_src, const int* e_dst, const float* ew,
                          const int* off_src, const int* eid_src,
                          const int* colc, const float* sc, float* Ac){
    int e1 = blockIdx.x * blockDim.x + threadIdx.x;
    if (e1 >= NE) return;
    int i = (e1 < E0S) ? e_src[e1] : e1 - E0S;
    int j = (e1 < E0S) ? e_dst[e1] : e1 - E0S;
    float w1 = (e1 < E0S) ? ew[e1] : 1.0f;
    int ilo = off_src[i], ihi = off_src[i+1];
    int jlo = off_src[j], jhi = off_src[j+1];
    for (int ta = ilo; ta < ihi; ++ta){
        int ea = eid_src[ta];
        int ca = colc[ea];
        if (ca < 0) continue;
        float va = sc[ea] * w1;
        float* rowp = Ac + (size_t)ca * KK;
        for (int tb = jlo; tb < jhi; ++tb){
            int eb = eid_src[tb];
            int cb = colc[eb];
            if (cb < 0) continue;
            atomicAdd(&rowp[cb], va * sc[eb]);
        }
    }
}

// ---------------- zero diagonal of A_c ----------------
__global__ void diag_kernel(float* Ac){
    int r = blockIdx.x * blockDim.x + threadIdx.x;
    if (r < KK) Ac[(size_t)r * KK + r] = 0.f;
}

extern "C" void kernel_launch(void* const* d_in, const int* in_sizes, int n_in,
                              void* d_out, int out_size, void* d_ws, size_t ws_size,
                              hipStream_t stream){
    const float* x     = (const float*)d_in[0];
    const int*   ei    = (const int*)d_in[1];
    const float* ew    = (const float*)d_in[2];
    const float* lin_w = (const float*)d_in[3];
    const float* lin_b = (const float*)d_in[4];
    const float* att_w = (const float*)d_in[5];
    const float* att_b = (const float*)d_in[6];
    const float* le1_w = (const float*)d_in[7];
    const float* le1_b = (const float*)d_in[8];
    const float* le2_w = (const float*)d_in[9];
    const float* le3_w = (const float*)d_in[10];
    const float* le3_b = (const float*)d_in[11];

    const int* e_src = ei;
    const int* e_dst = ei + E0S;

    float* out    = (float*)d_out;
    float* x_out  = out;                                   // KK*DD
    float* Ac     = out + (size_t)KK * DD;                 // KK*KK
    float* operm  = out + (size_t)KK * DD + (size_t)KK * KK; // KK

    // workspace carve-up (all 4-byte elements)
    char* wp = (char*)d_ws;
    auto alloc_i = [&](size_t n){ int* p = (int*)wp; wp += n * sizeof(int); return p; };
    auto alloc_f = [&](size_t n){ float* p = (float*)wp; wp += n * sizeof(float); return p; };

    int* deg_dst = alloc_i(NN);
    int* deg_src = alloc_i(NN);
    int* off_dst = alloc_i(NN + 1);
    int* off_src = alloc_i(NN + 1);
    int* cur_dst = alloc_i(NN);
    int* cur_src = alloc_i(NN);
    int* eid_dst = alloc_i(NE);
    int* eid_src = alloc_i(NE);
    int* colmap  = alloc_i(NN);
    int* perm    = alloc_i(KK);
    int* colc    = alloc_i(NE);
    float* q_s   = alloc_f(NN);
    float* p_s   = alloc_f(NN);
    float* a_    = alloc_f(NN);
    float* b_    = alloc_f(NN);
    float* c_    = alloc_f(NN);
    float* fit   = alloc_f(NN);
    float* sc    = alloc_f(NE);
    float* x_q   = alloc_f((size_t)NN * DD);
    float* x_ql  = alloc_f((size_t)NN * DD);
    float* xn    = alloc_f((size_t)NN * DD);
    (void)ws_size; (void)n_in; (void)in_sizes; (void)out_size;

    const int EB = (NE + 255) / 256;

    init_kernel<<<2048, 256, 0, stream>>>(deg_dst, deg_src, colmap, Ac);
    count_kernel<<<EB, 256, 0, stream>>>(e_src, e_dst, deg_dst, deg_src);
    scan_kernel<<<2, 1024, 0, stream>>>(deg_dst, off_dst, cur_dst, deg_src, off_src, cur_src);
    fill_kernel<<<EB, 256, 0, stream>>>(e_src, e_dst, cur_dst, cur_src, eid_dst, eid_src);
    segsort_kernel<<<(2 * NN + 255) / 256, 256, 0, stream>>>(off_dst, eid_dst, off_src, eid_src);
    segmax_kernel<<<NN, 256, 0, stream>>>(x, off_dst, eid_dst, e_src, x_q);
    lin_kernel<<<NN / LROWS, 256, 0, stream>>>(x_q, lin_w, lin_b, x_ql);
    nodedots_kernel<<<NN, 256, 0, stream>>>(x, x_ql, att_w, q_s, p_s);
    softmax_kernel<<<NN / 4, 256, 0, stream>>>(off_dst, eid_dst, e_src, q_s, p_s, att_b, sc);
    xn_kernel<<<NN, 256, 0, stream>>>(x, off_dst, eid_dst, e_src, sc, xn);
    fitdots_kernel<<<NN, 256, 0, stream>>>(xn, le1_w, le1_b, le2_w, le3_w, le3_b, a_, b_, c_);
    fitness_kernel<<<NN / 4, 256, 0, stream>>>(off_dst, eid_dst, e_src, a_, b_, c_, fit);
    topk_kernel<<<1, 1024, 0, stream>>>(fit, perm, colmap, operm);
    xout_kernel<<<KK, 256, 0, stream>>>(xn, fit, perm, x_out);
    colc_kernel<<<EB, 256, 0, stream>>>(e_dst, colmap, colc);
    ac_kernel<<<EB, 256, 0, stream>>>(e_src, e_dst, ew, off_src, eid_src, colc, sc, Ac);
    diag_kernel<<<(KK + 255) / 256, 256, 0, stream>>>(Ac);
}

// Round 2
// 549.154 us; speedup vs baseline: 5.6959x; 5.6959x over previous
//
#include <hip/hip_runtime.h>
#include <cstdint>
#include <cstddef>
#include <math.h>

#define NN   4096
#define DD   256
#define E0S  131072
#define NE   (E0S + NN)     // 135168 edges incl. self loops
#define KK   2048
#define NEG_SLOPE 0.2f

// edge accessors: e < E0S -> from input arrays; else self-loop (e - E0S)
__device__ __forceinline__ int esrc(const int* s, int e){ return e < E0S ? s[e] : e - E0S; }
__device__ __forceinline__ int edst(const int* d, int e){ return e < E0S ? d[e] : e - E0S; }

// ---------------- init: zero degree arrays, colmap=-1, zero A_c ----------------
__global__ void init_kernel(int* deg_dst, int* deg_src, int* colmap, float* Ac){
    int i = blockIdx.x * blockDim.x + threadIdx.x;
    int stride = gridDim.x * blockDim.x;
    for (size_t t = i; t < (size_t)KK * KK; t += stride) Ac[t] = 0.f;
    for (int t = i; t < NN; t += stride){ deg_dst[t] = 0; deg_src[t] = 0; colmap[t] = -1; }
}

// ---------------- degree count ----------------
__global__ void count_kernel(const int* e_src, const int* e_dst, int* deg_dst, int* deg_src){
    int e = blockIdx.x * blockDim.x + threadIdx.x;
    if (e < NE){
        atomicAdd(&deg_dst[edst(e_dst, e)], 1);
        atomicAdd(&deg_src[esrc(e_src, e)], 1);
    }
}

// ---------------- exclusive scan of degrees (one block per array) ----------------
__global__ void __launch_bounds__(1024) scan_kernel(const int* degA, int* offA, int* curA,
                                                    const int* degB, int* offB, int* curB){
    const int* deg = (blockIdx.x == 0) ? degA : degB;
    int* off = (blockIdx.x == 0) ? offA : offB;
    int* cur = (blockIdx.x == 0) ? curA : curB;
    __shared__ int part[1024];
    int t = threadIdx.x;
    int base = t * 4;
    int s0 = deg[base], s1 = deg[base+1], s2 = deg[base+2], s3 = deg[base+3];
    int tot = s0 + s1 + s2 + s3;
    part[t] = tot;
    __syncthreads();
    for (int d = 1; d < 1024; d <<= 1){
        int v = (t >= d) ? part[t - d] : 0;
        __syncthreads();
        part[t] += v;
        __syncthreads();
    }
    int excl = part[t] - tot;
    off[base]   = excl;            cur[base]   = excl;
    off[base+1] = excl + s0;       cur[base+1] = excl + s0;
    off[base+2] = excl + s0 + s1;  cur[base+2] = excl + s0 + s1;
    off[base+3] = excl + s0 + s1 + s2; cur[base+3] = excl + s0 + s1 + s2;
    if (t == 1023) off[NN] = part[1023];
}

// ---------------- CSR fill ----------------
__global__ void fill_kernel(const int* e_src, const int* e_dst, int* cur_dst, int* cur_src,
                            int* eid_dst, int* eid_src){
    int e = blockIdx.x * blockDim.x + threadIdx.x;
    if (e < NE){
        int p = atomicAdd(&cur_dst[edst(e_dst, e)], 1); eid_dst[p] = e;
        int q = atomicAdd(&cur_src[esrc(e_src, e)], 1); eid_src[q] = e;
    }
}

// ---------------- sort each CSR segment (determinism) ----------------
__global__ void segsort_kernel(const int* off_dst, int* eid_dst, const int* off_src, int* eid_src){
    int n = blockIdx.x * blockDim.x + threadIdx.x;
    const int* off; int* eid;
    if (n < NN){ off = off_dst; eid = eid_dst; }
    else if (n < 2 * NN){ off = off_src; eid = eid_src; n -= NN; }
    else return;
    int lo = off[n], hi = off[n+1];
    for (int i = lo + 1; i < hi; ++i){
        int v = eid[i]; int j = i - 1;
        while (j >= lo && eid[j] > v){ eid[j+1] = eid[j]; --j; }
        eid[j+1] = v;
    }
}

// ---------------- x_q = segment_max(x[src], dst) : one block per node ----------------
__global__ void segmax_kernel(const float* x, const int* off, const int* eid, const int* e_src,
                              float* x_q){
    int n = blockIdx.x, d = threadIdx.x;
    int lo = off[n], hi = off[n+1];
    float m = -INFINITY;
    for (int t = lo; t < hi; ++t){
        int e = eid[t];
        int s = esrc(e_src, e);
        m = fmaxf(m, x[(size_t)s * DD + d]);
    }
    x_q[(size_t)n * DD + d] = m;
}

// ---------------- x_q_lin = x_q @ lin_w + lin_b ----------------
#define LROWS 8
__global__ void lin_kernel(const float* x_q, const float* w, const float* b, float* out){
    __shared__ float xs[LROWS][DD];
    int col = threadIdx.x;
    int r0 = blockIdx.x * LROWS;
    for (int r = 0; r < LROWS; ++r) xs[r][col] = x_q[(size_t)(r0 + r) * DD + col];
    __syncthreads();
    float acc[LROWS];
    float bc = b[col];
    #pragma unroll
    for (int r = 0; r < LROWS; ++r) acc[r] = bc;
    for (int kk = 0; kk < DD; ++kk){
        float wv = w[(size_t)kk * DD + col];
        #pragma unroll
        for (int r = 0; r < LROWS; ++r) acc[r] = fmaf(xs[r][kk], wv, acc[r]);
    }
    for (int r = 0; r < LROWS; ++r) out[(size_t)(r0 + r) * DD + col] = acc[r];
}

// ---------------- per-node attention dots: q_s = x_q_lin . att_w[0:D], p_s = x . att_w[D:2D] ----
__global__ void nodedots_kernel(const float* x, const float* x_q_lin, const float* att_w,
                                float* q_s, float* p_s){
    int n = blockIdx.x, t = threadIdx.x;
    float v1 = x_q_lin[(size_t)n * DD + t] * att_w[t];
    float v2 = x[(size_t)n * DD + t] * att_w[DD + t];
    __shared__ float s1[256], s2[256];
    s1[t] = v1; s2[t] = v2;
    __syncthreads();
    for (int d = 128; d > 0; d >>= 1){
        if (t < d){ s1[t] += s1[t + d]; s2[t] += s2[t + d]; }
        __syncthreads();
    }
    if (t == 0){ q_s[n] = s1[0]; p_s[n] = s2[0]; }
}

// ---------------- per-dst segment softmax of leaky_relu scores (one wave per node) --------
__global__ void softmax_kernel(const int* off, const int* eid, const int* e_src,
                               const float* q_s, const float* p_s, const float* att_b,
                               float* sc){
    int wave = threadIdx.x >> 6;
    int lane = threadIdx.x & 63;
    int n = blockIdx.x * 4 + wave;
    int lo = off[n], hi = off[n+1];
    float ab = att_b[0];
    float qn = q_s[n];
    float m = -INFINITY;
    for (int t = lo + lane; t < hi; t += 64){
        int e = eid[t];
        float s = qn + p_s[esrc(e_src, e)] + ab;
        s = (s > 0.f) ? s : NEG_SLOPE * s;
        m = fmaxf(m, s);
    }
    #pragma unroll
    for (int d = 32; d > 0; d >>= 1) m = fmaxf(m, __shfl_xor(m, d));
    float sum = 0.f;
    for (int t = lo + lane; t < hi; t += 64){
        int e = eid[t];
        float s = qn + p_s[esrc(e_src, e)] + ab;
        s = (s > 0.f) ? s : NEG_SLOPE * s;
        float ex = expf(s - m);
        sc[e] = ex;
        sum += ex;
    }
    #pragma unroll
    for (int d = 32; d > 0; d >>= 1) sum += __shfl_xor(sum, d);
    float inv = 1.f / sum;
    for (int t = lo + lane; t < hi; t += 64){
        sc[eid[t]] *= inv;
    }
}

// ---------------- xn = segment_sum(x[src] * sc, dst) : one block per node ----------------
__global__ void xn_kernel(const float* x, const int* off, const int* eid, const int* e_src,
                          const float* sc, float* xn){
    int n = blockIdx.x, d = threadIdx.x;
    int lo = off[n], hi = off[n+1];
    float acc = 0.f;
    for (int t = lo; t < hi; ++t){
        int e = eid[t];
        acc = fmaf(sc[e], x[(size_t)esrc(e_src, e) * DD + d], acc);
    }
    xn[(size_t)n * DD + d] = acc;
}

// ---------------- LEConv dots ----------------
__global__ void fitdots_kernel(const float* xn, const float* le1_w, const float* le1_b,
                               const float* le2_w, const float* le3_w, const float* le3_b,
                               float* a_, float* b_, float* c_){
    int n = blockIdx.x, t = threadIdx.x;
    float xv = xn[(size_t)n * DD + t];
    __shared__ float s1[256], s2[256], s3[256];
    s1[t] = xv * le1_w[t];
    s2[t] = xv * le2_w[t];
    s3[t] = xv * le3_w[t];
    __syncthreads();
    for (int d = 128; d > 0; d >>= 1){
        if (t < d){ s1[t] += s1[t+d]; s2[t] += s2[t+d]; s3[t] += s3[t+d]; }
        __syncthreads();
    }
    if (t == 0){
        a_[n] = s1[0] + le1_b[0];
        b_[n] = s2[0];
        c_[n] = s3[0] + le3_b[0];
    }
}

// ---------------- fitness = sigmoid(segsum(a[src]-b[dst]) + c) (one wave per node) --------
__global__ void fitness_kernel(const int* off, const int* eid, const int* e_src,
                               const float* a_, const float* b_, const float* c_,
                               float* fit){
    int wave = threadIdx.x >> 6;
    int lane = threadIdx.x & 63;
    int n = blockIdx.x * 4 + wave;
    int lo = off[n], hi = off[n+1];
    float bn = b_[n];
    float s = 0.f;
    for (int t = lo + lane; t < hi; t += 64){
        int e = eid[t];
        s += a_[esrc(e_src, e)] - bn;
    }
    #pragma unroll
    for (int d = 32; d > 0; d >>= 1) s += __shfl_xor(s, d);
    if (lane == 0){
        float z = s + c_[n];
        fit[n] = 1.f / (1.f + expf(-z));
    }
}

// ---------------- top-k via bitonic sort of (value desc, idx asc) keys ----------------
__global__ void __launch_bounds__(1024) topk_kernel(const float* fit, int* perm, int* colmap,
                                                    float* out_perm){
    __shared__ unsigned long long keys[NN];
    int t = threadIdx.x;
    for (int i = t; i < NN; i += 1024){
        unsigned int u = __float_as_uint(fit[i]);
        u = (u & 0x80000000u) ? ~u : (u | 0x80000000u);  // monotone map
        u = ~u;                                           // descending
        keys[i] = ((unsigned long long)u << 32) | (unsigned int)i;
    }
    __syncthreads();
    for (unsigned int ssize = 2; ssize <= NN; ssize <<= 1){
        for (unsigned int stride = ssize >> 1; stride > 0; stride >>= 1){
            for (int i = t; i < NN / 2; i += 1024){
                unsigned int idx = 2u * i - (i & (stride - 1u));
                unsigned int par = idx + stride;
                bool asc = ((idx & ssize) == 0u);
                unsigned long long a = keys[idx], b = keys[par];
                if ((a > b) == asc){ keys[idx] = b; keys[par] = a; }
            }
            __syncthreads();
        }
    }
    for (int i = t; i < KK; i += 1024){
        int node = (int)(keys[i] & 0xFFFFFFFFull);
        perm[i] = node;
        colmap[node] = i;
        out_perm[i] = (float)node;
    }
}

// ---------------- x_out = xn[perm] * fitness[perm] ----------------
__global__ void xout_kernel(const float* xn, const float* fit, const int* perm, float* x_out){
    int r = blockIdx.x, d = threadIdx.x;
    int p = perm[r];
    x_out[(size_t)r * DD + d] = xn[(size_t)p * DD + d] * fit[p];
}

// ---------------- colc[e] = colmap[dst(e)] ----------------
__global__ void colc_kernel(const int* e_dst, const int* colmap, int* colc){
    int e = blockIdx.x * blockDim.x + threadIdx.x;
    if (e < NE) colc[e] = colmap[edst(e_dst, e)];
}

// ---------------- T[i,:] = sum over out-edges e=(i,j): w_e * Sp[j,:]  (row in LDS) -------
__global__ void spgemm1_kernel(const int* e_dst, const float* ew,
                               const int* off_src, const int* eid_src,
                               const int* colc, const float* sc, float* T){
    __shared__ float row[KK];
    int i = blockIdx.x;
    for (int c = threadIdx.x; c < KK; c += 256) row[c] = 0.f;
    __syncthreads();
    int lo = off_src[i], hi = off_src[i+1];
    int wave = threadIdx.x >> 6, lane = threadIdx.x & 63;
    for (int t = lo + wave; t < hi; t += 4){
        int e = eid_src[t];                 // edge with src == i
        int j = edst(e_dst, e);
        float w1 = (e < E0S) ? ew[e] : 1.0f;
        int jlo = off_src[j], jhi = off_src[j+1];
        for (int u = jlo + lane; u < jhi; u += 64){
            int f = eid_src[u];             // edge with src == j
            int c = colc[f];
            if (c >= 0) atomicAdd(&row[c], w1 * sc[f]);
        }
    }
    __syncthreads();
    float* Trow = T + (size_t)i * KK;
    for (int c = threadIdx.x; c < KK; c += 256) Trow[c] = row[c];
}

// ---------------- A_c[r,:] = sum over in-edges e of perm[r]: sc[e] * T[src(e),:] ---------
__global__ void spgemm2_kernel(const int* perm, const int* off_dst, const int* eid_dst,
                               const int* e_src, const float* sc, const float* T, float* Ac){
    int r = blockIdx.x;
    int node = perm[r];
    int lo = off_dst[node], hi = off_dst[node+1];
    float acc[KK / 256];
    #pragma unroll
    for (int q = 0; q < KK / 256; ++q) acc[q] = 0.f;
    for (int t = lo; t < hi; ++t){
        int e = eid_dst[t];
        int i = esrc(e_src, e);
        float s = sc[e];
        const float* Trow = T + (size_t)i * KK;
        #pragma unroll
        for (int q = 0; q < KK / 256; ++q)
            acc[q] = fmaf(s, Trow[q * 256 + threadIdx.x], acc[q]);
    }
    float* rowp = Ac + (size_t)r * KK;
    #pragma unroll
    for (int q = 0; q < KK / 256; ++q){
        int c = q * 256 + threadIdx.x;
        rowp[c] = (c == r) ? 0.f : acc[q];
    }
}

// ---------------- fallback: edge-pair outer products with global atomics ----------------
__global__ void ac_kernel(const int* e_src, const int* e_dst, const float* ew,
                          const int* off_src, const int* eid_src,
                          const int* colc, const float* sc, float* Ac){
    int e1 = blockIdx.x * blockDim.x + threadIdx.x;
    if (e1 >= NE) return;
    int i = (e1 < E0S) ? e_src[e1] : e1 - E0S;
    int j = (e1 < E0S) ? e_dst[e1] : e1 - E0S;
    float w1 = (e1 < E0S) ? ew[e1] : 1.0f;
    int ilo = off_src[i], ihi = off_src[i+1];
    int jlo = off_src[j], jhi = off_src[j+1];
    for (int ta = ilo; ta < ihi; ++ta){
        int ea = eid_src[ta];
        int ca = colc[ea];
        if (ca < 0) continue;
        float va = sc[ea] * w1;
        float* rowp = Ac + (size_t)ca * KK;
        for (int tb = jlo; tb < jhi; ++tb){
            int eb = eid_src[tb];
            int cb = colc[eb];
            if (cb < 0) continue;
            atomicAdd(&rowp[cb], va * sc[eb]);
        }
    }
}

// ---------------- zero diagonal of A_c (fallback path) ----------------
__global__ void diag_kernel(float* Ac){
    int r = blockIdx.x * blockDim.x + threadIdx.x;
    if (r < KK) Ac[(size_t)r * KK + r] = 0.f;
}

extern "C" void kernel_launch(void* const* d_in, const int* in_sizes, int n_in,
                              void* d_out, int out_size, void* d_ws, size_t ws_size,
                              hipStream_t stream){
    const float* x     = (const float*)d_in[0];
    const int*   ei    = (const int*)d_in[1];
    const float* ew    = (const float*)d_in[2];
    const float* lin_w = (const float*)d_in[3];
    const float* lin_b = (const float*)d_in[4];
    const float* att_w = (const float*)d_in[5];
    const float* att_b = (const float*)d_in[6];
    const float* le1_w = (const float*)d_in[7];
    const float* le1_b = (const float*)d_in[8];
    const float* le2_w = (const float*)d_in[9];
    const float* le3_w = (const float*)d_in[10];
    const float* le3_b = (const float*)d_in[11];

    const int* e_src = ei;
    const int* e_dst = ei + E0S;

    float* out    = (float*)d_out;
    float* x_out  = out;                                     // KK*DD
    float* Ac     = out + (size_t)KK * DD;                   // KK*KK
    float* operm  = out + (size_t)KK * DD + (size_t)KK * KK; // KK

    // workspace carve-up (all 4-byte elements)
    char* wp = (char*)d_ws;
    auto alloc_i = [&](size_t n){ int* p = (int*)wp; wp += n * sizeof(int); return p; };
    auto alloc_f = [&](size_t n){ float* p = (float*)wp; wp += n * sizeof(float); return p; };

    int* deg_dst = alloc_i(NN);
    int* deg_src = alloc_i(NN);
    int* off_dst = alloc_i(NN + 1);
    int* off_src = alloc_i(NN + 1);
    int* cur_dst = alloc_i(NN);
    int* cur_src = alloc_i(NN);
    int* eid_dst = alloc_i(NE);
    int* eid_src = alloc_i(NE);
    int* colmap  = alloc_i(NN);
    int* perm    = alloc_i(KK);
    int* colc    = alloc_i(NE);
    float* q_s   = alloc_f(NN);
    float* p_s   = alloc_f(NN);
    float* a_    = alloc_f(NN);
    float* b_    = alloc_f(NN);
    float* c_    = alloc_f(NN);
    float* fit   = alloc_f(NN);
    float* sc    = alloc_f(NE);
    float* x_q   = alloc_f((size_t)NN * DD);
    float* x_ql  = alloc_f((size_t)NN * DD);
    float* xn    = alloc_f((size_t)NN * DD);
    float* T     = alloc_f((size_t)NN * KK);   // 32 MB dense intermediate for A_c
    bool dense_ok = ((size_t)(wp - (char*)d_ws) <= ws_size);
    (void)n_in; (void)in_sizes; (void)out_size;

    const int EB = (NE + 255) / 256;

    init_kernel<<<2048, 256, 0, stream>>>(deg_dst, deg_src, colmap, Ac);
    count_kernel<<<EB, 256, 0, stream>>>(e_src, e_dst, deg_dst, deg_src);
    scan_kernel<<<2, 1024, 0, stream>>>(deg_dst, off_dst, cur_dst, deg_src, off_src, cur_src);
    fill_kernel<<<EB, 256, 0, stream>>>(e_src, e_dst, cur_dst, cur_src, eid_dst, eid_src);
    segsort_kernel<<<(2 * NN + 255) / 256, 256, 0, stream>>>(off_dst, eid_dst, off_src, eid_src);
    segmax_kernel<<<NN, 256, 0, stream>>>(x, off_dst, eid_dst, e_src, x_q);
    lin_kernel<<<NN / LROWS, 256, 0, stream>>>(x_q, lin_w, lin_b, x_ql);
    nodedots_kernel<<<NN, 256, 0, stream>>>(x, x_ql, att_w, q_s, p_s);
    softmax_kernel<<<NN / 4, 256, 0, stream>>>(off_dst, eid_dst, e_src, q_s, p_s, att_b, sc);
    xn_kernel<<<NN, 256, 0, stream>>>(x, off_dst, eid_dst, e_src, sc, xn);
    fitdots_kernel<<<NN, 256, 0, stream>>>(xn, le1_w, le1_b, le2_w, le3_w, le3_b, a_, b_, c_);
    fitness_kernel<<<NN / 4, 256, 0, stream>>>(off_dst, eid_dst, e_src, a_, b_, c_, fit);
    topk_kernel<<<1, 1024, 0, stream>>>(fit, perm, colmap, operm);
    xout_kernel<<<KK, 256, 0, stream>>>(xn, fit, perm, x_out);
    colc_kernel<<<EB, 256, 0, stream>>>(e_dst, colmap, colc);
    if (dense_ok){
        spgemm1_kernel<<<NN, 256, 0, stream>>>(e_dst, ew, off_src, eid_src, colc, sc, T);
        spgemm2_kernel<<<KK, 256, 0, stream>>>(perm, off_dst, eid_dst, e_src, sc, T, Ac);
    } else {
        ac_kernel<<<EB, 256, 0, stream>>>(e_src, e_dst, ew, off_src, eid_src, colc, sc, Ac);
        diag_kernel<<<(KK + 255) / 256, 256, 0, stream>>>(Ac);
    }
}

// Round 3
// 349.668 us; speedup vs baseline: 8.9454x; 1.5705x over previous
//
#include <hip/hip_runtime.h>
#include <cstdint>
#include <cstddef>
#include <math.h>

#define NN   4096
#define DD   256
#define E0S  131072
#define NE   (E0S + NN)     // 135168 edges incl. self loops
#define KK   2048
#define NEG_SLOPE 0.2f
#define SEGCAP 256          // max segment length handled by the fast wave sort

// edge accessors: e < E0S -> from input arrays; else self-loop (e - E0S)
__device__ __forceinline__ int esrc(const int* s, int e){ return e < E0S ? s[e] : e - E0S; }
__device__ __forceinline__ int edst(const int* d, int e){ return e < E0S ? d[e] : e - E0S; }

// ---------------- init: zero degree arrays, colmap=-1, (optionally) zero A_c ------------
__global__ void init_kernel(int* deg_dst, int* deg_src, int* colmap, float* Ac, int zero_ac){
    int i = blockIdx.x * blockDim.x + threadIdx.x;
    int stride = gridDim.x * blockDim.x;
    if (zero_ac){
        for (size_t t = i; t < (size_t)KK * KK; t += stride) Ac[t] = 0.f;
    }
    for (int t = i; t < NN; t += stride){ deg_dst[t] = 0; deg_src[t] = 0; colmap[t] = -1; }
}

// ---------------- degree count ----------------
__global__ void count_kernel(const int* e_src, const int* e_dst, int* deg_dst, int* deg_src){
    int e = blockIdx.x * blockDim.x + threadIdx.x;
    if (e < NE){
        atomicAdd(&deg_dst[edst(e_dst, e)], 1);
        atomicAdd(&deg_src[esrc(e_src, e)], 1);
    }
}

// ---------------- exclusive scan of degrees (one block per array) ----------------
__global__ void __launch_bounds__(1024) scan_kernel(const int* degA, int* offA, int* curA,
                                                    const int* degB, int* offB, int* curB){
    const int* deg = (blockIdx.x == 0) ? degA : degB;
    int* off = (blockIdx.x == 0) ? offA : offB;
    int* cur = (blockIdx.x == 0) ? curA : curB;
    __shared__ int part[1024];
    int t = threadIdx.x;
    int base = t * 4;
    int s0 = deg[base], s1 = deg[base+1], s2 = deg[base+2], s3 = deg[base+3];
    int tot = s0 + s1 + s2 + s3;
    part[t] = tot;
    __syncthreads();
    for (int d = 1; d < 1024; d <<= 1){
        int v = (t >= d) ? part[t - d] : 0;
        __syncthreads();
        part[t] += v;
        __syncthreads();
    }
    int excl = part[t] - tot;
    off[base]   = excl;            cur[base]   = excl;
    off[base+1] = excl + s0;       cur[base+1] = excl + s0;
    off[base+2] = excl + s0 + s1;  cur[base+2] = excl + s0 + s1;
    off[base+3] = excl + s0 + s1 + s2; cur[base+3] = excl + s0 + s1 + s2;
    if (t == 1023) off[NN] = part[1023];
}

// ---------------- CSR fill ----------------
__global__ void fill_kernel(const int* e_src, const int* e_dst, int* cur_dst, int* cur_src,
                            int* eid_dst, int* eid_src){
    int e = blockIdx.x * blockDim.x + threadIdx.x;
    if (e < NE){
        int p = atomicAdd(&cur_dst[edst(e_dst, e)], 1); eid_dst[p] = e;
        int q = atomicAdd(&cur_src[esrc(e_src, e)], 1); eid_src[q] = e;
    }
}

// ---------------- sort each CSR segment ascending (determinism): rank-by-count ----------
// one wave per segment; 4 waves (256 threads) per block; grid sized exactly so no wave
// early-returns before the block barrier.
__global__ void segsort_kernel(const int* off_dst, int* eid_dst, const int* off_src, int* eid_src){
    __shared__ int buf[4][SEGCAP];
    int wid  = (blockIdx.x * blockDim.x + threadIdx.x) >> 6;   // global wave id in [0, 2*NN)
    int lane = threadIdx.x & 63;
    int w    = threadIdx.x >> 6;
    const int* off; int* eid; int n;
    if (wid < NN){ off = off_dst; eid = eid_dst; n = wid; }
    else         { off = off_src; eid = eid_src; n = wid - NN; }
    int lo = off[n], hi = off[n+1];
    int L = hi - lo;
    int Lc = (L <= SEGCAP) ? L : SEGCAP;
    for (int i = lane; i < Lc; i += 64) buf[w][i] = eid[lo + i];
    __syncthreads();
    if (L <= SEGCAP){
        for (int i = lane; i < L; i += 64){
            int v = buf[w][i];
            int r = 0;
            for (int j = 0; j < L; ++j) r += (buf[w][j] < v);
            eid[lo + r] = v;
        }
    } else if (lane == 0){
        // pathological fallback (never expected at this size)
        for (int i = lo + 1; i < hi; ++i){
            int v = eid[i]; int j = i - 1;
            while (j >= lo && eid[j] > v){ eid[j+1] = eid[j]; --j; }
            eid[j+1] = v;
        }
    }
}

// ---------------- x_q = segment_max(x[src], dst) : one block per node ----------------
__global__ void segmax_kernel(const float* x, const int* off, const int* eid, const int* e_src,
                              float* x_q){
    int n = blockIdx.x, d = threadIdx.x;
    int lo = off[n], hi = off[n+1];
    float m = -INFINITY;
    for (int t = lo; t < hi; ++t){
        int e = eid[t];
        int s = esrc(e_src, e);
        m = fmaxf(m, x[(size_t)s * DD + d]);
    }
    x_q[(size_t)n * DD + d] = m;
}

// ---------------- x_q_lin = x_q @ lin_w + lin_b ----------------
#define LROWS 8
__global__ void lin_kernel(const float* x_q, const float* w, const float* b, float* out){
    __shared__ float xs[LROWS][DD];
    int col = threadIdx.x;
    int r0 = blockIdx.x * LROWS;
    for (int r = 0; r < LROWS; ++r) xs[r][col] = x_q[(size_t)(r0 + r) * DD + col];
    __syncthreads();
    float acc[LROWS];
    float bc = b[col];
    #pragma unroll
    for (int r = 0; r < LROWS; ++r) acc[r] = bc;
    for (int kk = 0; kk < DD; ++kk){
        float wv = w[(size_t)kk * DD + col];
        #pragma unroll
        for (int r = 0; r < LROWS; ++r) acc[r] = fmaf(xs[r][kk], wv, acc[r]);
    }
    for (int r = 0; r < LROWS; ++r) out[(size_t)(r0 + r) * DD + col] = acc[r];
}

// ---------------- per-node attention dots: q_s = x_q_lin . att_w[0:D], p_s = x . att_w[D:2D] ----
__global__ void nodedots_kernel(const float* x, const float* x_q_lin, const float* att_w,
                                float* q_s, float* p_s){
    int n = blockIdx.x, t = threadIdx.x;
    float v1 = x_q_lin[(size_t)n * DD + t] * att_w[t];
    float v2 = x[(size_t)n * DD + t] * att_w[DD + t];
    __shared__ float s1[256], s2[256];
    s1[t] = v1; s2[t] = v2;
    __syncthreads();
    for (int d = 128; d > 0; d >>= 1){
        if (t < d){ s1[t] += s1[t + d]; s2[t] += s2[t + d]; }
        __syncthreads();
    }
    if (t == 0){ q_s[n] = s1[0]; p_s[n] = s2[0]; }
}

// ---------------- per-dst segment softmax of leaky_relu scores (one wave per node) --------
__global__ void softmax_kernel(const int* off, const int* eid, const int* e_src,
                               const float* q_s, const float* p_s, const float* att_b,
                               float* sc){
    int wave = threadIdx.x >> 6;
    int lane = threadIdx.x & 63;
    int n = blockIdx.x * 4 + wave;
    int lo = off[n], hi = off[n+1];
    float ab = att_b[0];
    float qn = q_s[n];
    float m = -INFINITY;
    for (int t = lo + lane; t < hi; t += 64){
        int e = eid[t];
        float s = qn + p_s[esrc(e_src, e)] + ab;
        s = (s > 0.f) ? s : NEG_SLOPE * s;
        m = fmaxf(m, s);
    }
    #pragma unroll
    for (int d = 32; d > 0; d >>= 1) m = fmaxf(m, __shfl_xor(m, d));
    float sum = 0.f;
    for (int t = lo + lane; t < hi; t += 64){
        int e = eid[t];
        float s = qn + p_s[esrc(e_src, e)] + ab;
        s = (s > 0.f) ? s : NEG_SLOPE * s;
        float ex = expf(s - m);
        sc[e] = ex;
        sum += ex;
    }
    #pragma unroll
    for (int d = 32; d > 0; d >>= 1) sum += __shfl_xor(sum, d);
    float inv = 1.f / sum;
    for (int t = lo + lane; t < hi; t += 64){
        sc[eid[t]] *= inv;
    }
}

// ---------------- xn = segment_sum(x[src] * sc, dst) : one block per node ----------------
__global__ void xn_kernel(const float* x, const int* off, const int* eid, const int* e_src,
                          const float* sc, float* xn){
    int n = blockIdx.x, d = threadIdx.x;
    int lo = off[n], hi = off[n+1];
    float acc = 0.f;
    for (int t = lo; t < hi; ++t){
        int e = eid[t];
        acc = fmaf(sc[e], x[(size_t)esrc(e_src, e) * DD + d], acc);
    }
    xn[(size_t)n * DD + d] = acc;
}

// ---------------- LEConv dots ----------------
__global__ void fitdots_kernel(const float* xn, const float* le1_w, const float* le1_b,
                               const float* le2_w, const float* le3_w, const float* le3_b,
                               float* a_, float* b_, float* c_){
    int n = blockIdx.x, t = threadIdx.x;
    float xv = xn[(size_t)n * DD + t];
    __shared__ float s1[256], s2[256], s3[256];
    s1[t] = xv * le1_w[t];
    s2[t] = xv * le2_w[t];
    s3[t] = xv * le3_w[t];
    __syncthreads();
    for (int d = 128; d > 0; d >>= 1){
        if (t < d){ s1[t] += s1[t+d]; s2[t] += s2[t+d]; s3[t] += s3[t+d]; }
        __syncthreads();
    }
    if (t == 0){
        a_[n] = s1[0] + le1_b[0];
        b_[n] = s2[0];
        c_[n] = s3[0] + le3_b[0];
    }
}

// ---------------- fitness = sigmoid(segsum(a[src]-b[dst]) + c) (one wave per node) --------
__global__ void fitness_kernel(const int* off, const int* eid, const int* e_src,
                               const float* a_, const float* b_, const float* c_,
                               float* fit){
    int wave = threadIdx.x >> 6;
    int lane = threadIdx.x & 63;
    int n = blockIdx.x * 4 + wave;
    int lo = off[n], hi = off[n+1];
    float bn = b_[n];
    float s = 0.f;
    for (int t = lo + lane; t < hi; t += 64){
        int e = eid[t];
        s += a_[esrc(e_src, e)] - bn;
    }
    #pragma unroll
    for (int d = 32; d > 0; d >>= 1) s += __shfl_xor(s, d);
    if (lane == 0){
        float z = s + c_[n];
        fit[n] = 1.f / (1.f + expf(-z));
    }
}

// ---------------- top-k via bitonic sort of (value desc, idx asc) keys ----------------
__global__ void __launch_bounds__(1024) topk_kernel(const float* fit, int* perm, int* colmap,
                                                    float* out_perm){
    __shared__ unsigned long long keys[NN];
    int t = threadIdx.x;
    for (int i = t; i < NN; i += 1024){
        unsigned int u = __float_as_uint(fit[i]);
        u = (u & 0x80000000u) ? ~u : (u | 0x80000000u);  // monotone map
        u = ~u;                                           // descending
        keys[i] = ((unsigned long long)u << 32) | (unsigned int)i;
    }
    __syncthreads();
    for (unsigned int ssize = 2; ssize <= NN; ssize <<= 1){
        for (unsigned int stride = ssize >> 1; stride > 0; stride >>= 1){
            for (int i = t; i < NN / 2; i += 1024){
                unsigned int idx = 2u * i - (i & (stride - 1u));
                unsigned int par = idx + stride;
                bool asc = ((idx & ssize) == 0u);
                unsigned long long a = keys[idx], b = keys[par];
                if ((a > b) == asc){ keys[idx] = b; keys[par] = a; }
            }
            __syncthreads();
        }
    }
    for (int i = t; i < KK; i += 1024){
        int node = (int)(keys[i] & 0xFFFFFFFFull);
        perm[i] = node;
        colmap[node] = i;
        out_perm[i] = (float)node;
    }
}

// ---------------- x_out = xn[perm] * fitness[perm] ----------------
__global__ void xout_kernel(const float* xn, const float* fit, const int* perm, float* x_out){
    int r = blockIdx.x, d = threadIdx.x;
    int p = perm[r];
    x_out[(size_t)r * DD + d] = xn[(size_t)p * DD + d] * fit[p];
}

// ---------------- colc[e] = colmap[dst(e)] ----------------
__global__ void colc_kernel(const int* e_dst, const int* colmap, int* colc){
    int e = blockIdx.x * blockDim.x + threadIdx.x;
    if (e < NE) colc[e] = colmap[edst(e_dst, e)];
}

// ---------------- T[i,:] = sum over out-edges e=(i,j): w_e * Sp[j,:]  (row in LDS) -------
__global__ void spgemm1_kernel(const int* e_dst, const float* ew,
                               const int* off_src, const int* eid_src,
                               const int* colc, const float* sc, float* T){
    __shared__ float row[KK];
    int i = blockIdx.x;
    for (int c = threadIdx.x; c < KK; c += 256) row[c] = 0.f;
    __syncthreads();
    int lo = off_src[i], hi = off_src[i+1];
    int wave = threadIdx.x >> 6, lane = threadIdx.x & 63;
    for (int t = lo + wave; t < hi; t += 4){
        int e = eid_src[t];                 // edge with src == i
        int j = edst(e_dst, e);
        float w1 = (e < E0S) ? ew[e] : 1.0f;
        int jlo = off_src[j], jhi = off_src[j+1];
        for (int u = jlo + lane; u < jhi; u += 64){
            int f = eid_src[u];             // edge with src == j
            int c = colc[f];
            if (c >= 0) atomicAdd(&row[c], w1 * sc[f]);
        }
    }
    __syncthreads();
    float* Trow = T + (size_t)i * KK;
    for (int c = threadIdx.x; c < KK; c += 256) Trow[c] = row[c];
}

// ---------------- A_c[r,:] = sum over in-edges e of perm[r]: sc[e] * T[src(e),:] ---------
__global__ void spgemm2_kernel(const int* perm, const int* off_dst, const int* eid_dst,
                               const int* e_src, const float* sc, const float* T, float* Ac){
    int r = blockIdx.x;
    int node = perm[r];
    int lo = off_dst[node], hi = off_dst[node+1];
    float acc[KK / 256];
    #pragma unroll
    for (int q = 0; q < KK / 256; ++q) acc[q] = 0.f;
    for (int t = lo; t < hi; ++t){
        int e = eid_dst[t];
        int i = esrc(e_src, e);
        float s = sc[e];
        const float* Trow = T + (size_t)i * KK;
        #pragma unroll
        for (int q = 0; q < KK / 256; ++q)
            acc[q] = fmaf(s, Trow[q * 256 + threadIdx.x], acc[q]);
    }
    float* rowp = Ac + (size_t)r * KK;
    #pragma unroll
    for (int q = 0; q < KK / 256; ++q){
        int c = q * 256 + threadIdx.x;
        rowp[c] = (c == r) ? 0.f : acc[q];
    }
}

// ---------------- fallback: edge-pair outer products with global atomics ----------------
__global__ void ac_kernel(const int* e_src, const int* e_dst, const float* ew,
                          const int* off_src, const int* eid_src,
                          const int* colc, const float* sc, float* Ac){
    int e1 = blockIdx.x * blockDim.x + threadIdx.x;
    if (e1 >= NE) return;
    int i = (e1 < E0S) ? e_src[e1] : e1 - E0S;
    int j = (e1 < E0S) ? e_dst[e1] : e1 - E0S;
    float w1 = (e1 < E0S) ? ew[e1] : 1.0f;
    int ilo = off_src[i], ihi = off_src[i+1];
    int jlo = off_src[j], jhi = off_src[j+1];
    for (int ta = ilo; ta < ihi; ++ta){
        int ea = eid_src[ta];
        int ca = colc[ea];
        if (ca < 0) continue;
        float va = sc[ea] * w1;
        float* rowp = Ac + (size_t)ca * KK;
        for (int tb = jlo; tb < jhi; ++tb){
            int eb = eid_src[tb];
            int cb = colc[eb];
            if (cb < 0) continue;
            atomicAdd(&rowp[cb], va * sc[eb]);
        }
    }
}

// ---------------- zero diagonal of A_c (fallback path) ----------------
__global__ void diag_kernel(float* Ac){
    int r = blockIdx.x * blockDim.x + threadIdx.x;
    if (r < KK) Ac[(size_t)r * KK + r] = 0.f;
}

extern "C" void kernel_launch(void* const* d_in, const int* in_sizes, int n_in,
                              void* d_out, int out_size, void* d_ws, size_t ws_size,
                              hipStream_t stream){
    const float* x     = (const float*)d_in[0];
    const int*   ei    = (const int*)d_in[1];
    const float* ew    = (const float*)d_in[2];
    const float* lin_w = (const float*)d_in[3];
    const float* lin_b = (const float*)d_in[4];
    const float* att_w = (const float*)d_in[5];
    const float* att_b = (const float*)d_in[6];
    const float* le1_w = (const float*)d_in[7];
    const float* le1_b = (const float*)d_in[8];
    const float* le2_w = (const float*)d_in[9];
    const float* le3_w = (const float*)d_in[10];
    const float* le3_b = (const float*)d_in[11];

    const int* e_src = ei;
    const int* e_dst = ei + E0S;

    float* out    = (float*)d_out;
    float* x_out  = out;                                     // KK*DD
    float* Ac     = out + (size_t)KK * DD;                   // KK*KK
    float* operm  = out + (size_t)KK * DD + (size_t)KK * KK; // KK

    // workspace carve-up (all 4-byte elements)
    char* wp = (char*)d_ws;
    auto alloc_i = [&](size_t n){ int* p = (int*)wp; wp += n * sizeof(int); return p; };
    auto alloc_f = [&](size_t n){ float* p = (float*)wp; wp += n * sizeof(float); return p; };

    int* deg_dst = alloc_i(NN);
    int* deg_src = alloc_i(NN);
    int* off_dst = alloc_i(NN + 1);
    int* off_src = alloc_i(NN + 1);
    int* cur_dst = alloc_i(NN);
    int* cur_src = alloc_i(NN);
    int* eid_dst = alloc_i(NE);
    int* eid_src = alloc_i(NE);
    int* colmap  = alloc_i(NN);
    int* perm    = alloc_i(KK);
    int* colc    = alloc_i(NE);
    float* q_s   = alloc_f(NN);
    float* p_s   = alloc_f(NN);
    float* a_    = alloc_f(NN);
    float* b_    = alloc_f(NN);
    float* c_    = alloc_f(NN);
    float* fit   = alloc_f(NN);
    float* sc    = alloc_f(NE);
    float* x_q   = alloc_f((size_t)NN * DD);
    float* x_ql  = alloc_f((size_t)NN * DD);
    float* xn    = alloc_f((size_t)NN * DD);
    float* T     = alloc_f((size_t)NN * KK);   // 32 MB dense intermediate for A_c
    bool dense_ok = ((size_t)(wp - (char*)d_ws) <= ws_size);
    (void)n_in; (void)in_sizes; (void)out_size;

    const int EB = (NE + 255) / 256;

    init_kernel<<<2048, 256, 0, stream>>>(deg_dst, deg_src, colmap, Ac, dense_ok ? 0 : 1);
    count_kernel<<<EB, 256, 0, stream>>>(e_src, e_dst, deg_dst, deg_src);
    scan_kernel<<<2, 1024, 0, stream>>>(deg_dst, off_dst, cur_dst, deg_src, off_src, cur_src);
    fill_kernel<<<EB, 256, 0, stream>>>(e_src, e_dst, cur_dst, cur_src, eid_dst, eid_src);
    // one wave per segment, 2*NN segments, 4 waves/block -> exactly 2*NN/4 blocks
    segsort_kernel<<<(2 * NN) / 4, 256, 0, stream>>>(off_dst, eid_dst, off_src, eid_src);
    segmax_kernel<<<NN, 256, 0, stream>>>(x, off_dst, eid_dst, e_src, x_q);
    lin_kernel<<<NN / LROWS, 256, 0, stream>>>(x_q, lin_w, lin_b, x_ql);
    nodedots_kernel<<<NN, 256, 0, stream>>>(x, x_ql, att_w, q_s, p_s);
    softmax_kernel<<<NN / 4, 256, 0, stream>>>(off_dst, eid_dst, e_src, q_s, p_s, att_b, sc);
    xn_kernel<<<NN, 256, 0, stream>>>(x, off_dst, eid_dst, e_src, sc, xn);
    fitdots_kernel<<<NN, 256, 0, stream>>>(xn, le1_w, le1_b, le2_w, le3_w, le3_b, a_, b_, c_);
    fitness_kernel<<<NN / 4, 256, 0, stream>>>(off_dst, eid_dst, e_src, a_, b_, c_, fit);
    topk_kernel<<<1, 1024, 0, stream>>>(fit, perm, colmap, operm);
    xout_kernel<<<KK, 256, 0, stream>>>(xn, fit, perm, x_out);
    colc_kernel<<<EB, 256, 0, stream>>>(e_dst, colmap, colc);
    if (dense_ok){
        spgemm1_kernel<<<NN, 256, 0, stream>>>(e_dst, ew, off_src, eid_src, colc, sc, T);
        spgemm2_kernel<<<KK, 256, 0, stream>>>(perm, off_dst, eid_dst, e_src, sc, T, Ac);
    } else {
        ac_kernel<<<EB, 256, 0, stream>>>(e_src, e_dst, ew, off_src, eid_src, colc, sc, Ac);
        diag_kernel<<<(KK + 255) / 256, 256, 0, stream>>>(Ac);
    }
}

// Round 4
// 275.774 us; speedup vs baseline: 11.3423x; 1.2680x over previous
//
#include <hip/hip_runtime.h>
#include <cstdint>
#include <cstddef>
#include <math.h>

#define NN   4096
#define DD   256
#define E0S  131072
#define NE   (E0S + NN)     // 135168 edges incl. self loops
#define KK   2048
#define NEG_SLOPE 0.2f
#define SEGCAP 256          // max segment length staged in LDS

// edge accessors: e < E0S -> from input arrays; else self-loop (e - E0S)
__device__ __forceinline__ int esrc(const int* s, int e){ return e < E0S ? s[e] : e - E0S; }
__device__ __forceinline__ int edst(const int* d, int e){ return e < E0S ? d[e] : e - E0S; }

// ---------------- init: zero degree arrays, colmap=-1, (optionally) zero A_c ------------
__global__ void init_kernel(int* deg_dst, int* deg_src, int* colmap, float* Ac, int zero_ac){
    int i = blockIdx.x * blockDim.x + threadIdx.x;
    int stride = gridDim.x * blockDim.x;
    if (zero_ac){
        for (size_t t = i; t < (size_t)KK * KK; t += stride) Ac[t] = 0.f;
    }
    for (int t = i; t < NN; t += stride){ deg_dst[t] = 0; deg_src[t] = 0; colmap[t] = -1; }
}

// ---------------- degree count ----------------
__global__ void count_kernel(const int* e_src, const int* e_dst, int* deg_dst, int* deg_src){
    int e = blockIdx.x * blockDim.x + threadIdx.x;
    if (e < NE){
        atomicAdd(&deg_dst[edst(e_dst, e)], 1);
        atomicAdd(&deg_src[esrc(e_src, e)], 1);
    }
}

// ---------------- exclusive scan of degrees (one block per array) ----------------
__global__ void __launch_bounds__(1024) scan_kernel(const int* degA, int* offA, int* curA,
                                                    const int* degB, int* offB, int* curB){
    const int* deg = (blockIdx.x == 0) ? degA : degB;
    int* off = (blockIdx.x == 0) ? offA : offB;
    int* cur = (blockIdx.x == 0) ? curA : curB;
    __shared__ int part[1024];
    int t = threadIdx.x;
    int base = t * 4;
    int s0 = deg[base], s1 = deg[base+1], s2 = deg[base+2], s3 = deg[base+3];
    int tot = s0 + s1 + s2 + s3;
    part[t] = tot;
    __syncthreads();
    for (int d = 1; d < 1024; d <<= 1){
        int v = (t >= d) ? part[t - d] : 0;
        __syncthreads();
        part[t] += v;
        __syncthreads();
    }
    int excl = part[t] - tot;
    off[base]   = excl;            cur[base]   = excl;
    off[base+1] = excl + s0;       cur[base+1] = excl + s0;
    off[base+2] = excl + s0 + s1;  cur[base+2] = excl + s0 + s1;
    off[base+3] = excl + s0 + s1 + s2; cur[base+3] = excl + s0 + s1 + s2;
    if (t == 1023) off[NN] = part[1023];
}

// ---------------- CSR fill ----------------
__global__ void fill_kernel(const int* e_src, const int* e_dst, int* cur_dst, int* cur_src,
                            int* eid_dst, int* eid_src){
    int e = blockIdx.x * blockDim.x + threadIdx.x;
    if (e < NE){
        int p = atomicAdd(&cur_dst[edst(e_dst, e)], 1); eid_dst[p] = e;
        int q = atomicAdd(&cur_src[esrc(e_src, e)], 1); eid_src[q] = e;
    }
}

// ---------------- sort each CSR segment ascending (determinism): rank-by-count ----------
__global__ void segsort_kernel(const int* off_dst, int* eid_dst, const int* off_src, int* eid_src){
    __shared__ int buf[4][SEGCAP];
    int wid  = (blockIdx.x * blockDim.x + threadIdx.x) >> 6;   // global wave id in [0, 2*NN)
    int lane = threadIdx.x & 63;
    int w    = threadIdx.x >> 6;
    const int* off; int* eid; int n;
    if (wid < NN){ off = off_dst; eid = eid_dst; n = wid; }
    else         { off = off_src; eid = eid_src; n = wid - NN; }
    int lo = off[n], hi = off[n+1];
    int L = hi - lo;
    int Lc = (L <= SEGCAP) ? L : SEGCAP;
    for (int i = lane; i < Lc; i += 64) buf[w][i] = eid[lo + i];
    __syncthreads();
    if (L <= SEGCAP){
        for (int i = lane; i < L; i += 64){
            int v = buf[w][i];
            int r = 0;
            for (int j = 0; j < L; ++j) r += (buf[w][j] < v);
            eid[lo + r] = v;
        }
    } else if (lane == 0){
        // pathological fallback (never expected at this size)
        for (int i = lo + 1; i < hi; ++i){
            int v = eid[i]; int j = i - 1;
            while (j >= lo && eid[j] > v){ eid[j+1] = eid[j]; --j; }
            eid[j+1] = v;
        }
    }
}

// ---------------- x_q = segment_max(x[src], dst) : one block per node, staged srcs -------
__global__ void segmax_kernel(const float* x, const int* off, const int* eid, const int* e_src,
                              float* x_q){
    __shared__ int is_[SEGCAP];
    int n = blockIdx.x, d = threadIdx.x;
    int lo = off[n], hi = off[n+1];
    int L = hi - lo;
    int Ls = (L <= SEGCAP) ? L : SEGCAP;
    for (int t = d; t < Ls; t += 256) is_[t] = esrc(e_src, eid[lo + t]);
    __syncthreads();
    float m = -INFINITY;
    int t = 0;
    for (; t + 1 < Ls; t += 2){
        float v0 = x[(size_t)is_[t]   * DD + d];
        float v1 = x[(size_t)is_[t+1] * DD + d];
        m = fmaxf(m, fmaxf(v0, v1));
    }
    if (t < Ls) m = fmaxf(m, x[(size_t)is_[t] * DD + d]);
    for (t = Ls; t < L; ++t)  // overflow fallback
        m = fmaxf(m, x[(size_t)esrc(e_src, eid[lo + t]) * DD + d]);
    x_q[(size_t)n * DD + d] = m;
}

// ---------------- x_q_lin = x_q @ lin_w + lin_b ----------------
#define LROWS 8
__global__ void lin_kernel(const float* x_q, const float* w, const float* b, float* out){
    __shared__ float xs[LROWS][DD];
    int col = threadIdx.x;
    int r0 = blockIdx.x * LROWS;
    for (int r = 0; r < LROWS; ++r) xs[r][col] = x_q[(size_t)(r0 + r) * DD + col];
    __syncthreads();
    float acc[LROWS];
    float bc = b[col];
    #pragma unroll
    for (int r = 0; r < LROWS; ++r) acc[r] = bc;
    for (int kk = 0; kk < DD; ++kk){
        float wv = w[(size_t)kk * DD + col];
        #pragma unroll
        for (int r = 0; r < LROWS; ++r) acc[r] = fmaf(xs[r][kk], wv, acc[r]);
    }
    for (int r = 0; r < LROWS; ++r) out[(size_t)(r0 + r) * DD + col] = acc[r];
}

// ---------------- per-node attention dots: q_s = x_q_lin . att_w[0:D], p_s = x . att_w[D:2D] ----
__global__ void nodedots_kernel(const float* x, const float* x_q_lin, const float* att_w,
                                float* q_s, float* p_s){
    int n = blockIdx.x, t = threadIdx.x;
    float v1 = x_q_lin[(size_t)n * DD + t] * att_w[t];
    float v2 = x[(size_t)n * DD + t] * att_w[DD + t];
    __shared__ float s1[256], s2[256];
    s1[t] = v1; s2[t] = v2;
    __syncthreads();
    for (int d = 128; d > 0; d >>= 1){
        if (t < d){ s1[t] += s1[t + d]; s2[t] += s2[t + d]; }
        __syncthreads();
    }
    if (t == 0){ q_s[n] = s1[0]; p_s[n] = s2[0]; }
}

// ---------------- per-dst segment softmax of leaky_relu scores (one wave per node) --------
__global__ void softmax_kernel(const int* off, const int* eid, const int* e_src,
                               const float* q_s, const float* p_s, const float* att_b,
                               float* sc){
    int wave = threadIdx.x >> 6;
    int lane = threadIdx.x & 63;
    int n = blockIdx.x * 4 + wave;
    int lo = off[n], hi = off[n+1];
    float ab = att_b[0];
    float qn = q_s[n];
    float m = -INFINITY;
    for (int t = lo + lane; t < hi; t += 64){
        int e = eid[t];
        float s = qn + p_s[esrc(e_src, e)] + ab;
        s = (s > 0.f) ? s : NEG_SLOPE * s;
        m = fmaxf(m, s);
    }
    #pragma unroll
    for (int d = 32; d > 0; d >>= 1) m = fmaxf(m, __shfl_xor(m, d));
    float sum = 0.f;
    for (int t = lo + lane; t < hi; t += 64){
        int e = eid[t];
        float s = qn + p_s[esrc(e_src, e)] + ab;
        s = (s > 0.f) ? s : NEG_SLOPE * s;
        float ex = expf(s - m);
        sc[e] = ex;
        sum += ex;
    }
    #pragma unroll
    for (int d = 32; d > 0; d >>= 1) sum += __shfl_xor(sum, d);
    float inv = 1.f / sum;
    for (int t = lo + lane; t < hi; t += 64){
        sc[eid[t]] *= inv;
    }
}

// ---------------- xn = segment_sum(x[src] * sc, dst) : one block per node, staged ---------
__global__ void xn_kernel(const float* x, const int* off, const int* eid, const int* e_src,
                          const float* sc, float* xn){
    __shared__ int   is_[SEGCAP];
    __shared__ float ss_[SEGCAP];
    int n = blockIdx.x, d = threadIdx.x;
    int lo = off[n], hi = off[n+1];
    int L = hi - lo;
    int Ls = (L <= SEGCAP) ? L : SEGCAP;
    for (int t = d; t < Ls; t += 256){
        int e = eid[lo + t];
        is_[t] = esrc(e_src, e);
        ss_[t] = sc[e];
    }
    __syncthreads();
    float acc = 0.f;
    int t = 0;
    for (; t + 1 < Ls; t += 2){
        float v0 = x[(size_t)is_[t]   * DD + d];
        float v1 = x[(size_t)is_[t+1] * DD + d];
        acc = fmaf(ss_[t],   v0, acc);   // sequential order preserved
        acc = fmaf(ss_[t+1], v1, acc);
    }
    if (t < Ls) acc = fmaf(ss_[t], x[(size_t)is_[t] * DD + d], acc);
    for (t = Ls; t < L; ++t){            // overflow fallback
        int e = eid[lo + t];
        acc = fmaf(sc[e], x[(size_t)esrc(e_src, e) * DD + d], acc);
    }
    xn[(size_t)n * DD + d] = acc;
}

// ---------------- LEConv dots ----------------
__global__ void fitdots_kernel(const float* xn, const float* le1_w, const float* le1_b,
                               const float* le2_w, const float* le3_w, const float* le3_b,
                               float* a_, float* b_, float* c_){
    int n = blockIdx.x, t = threadIdx.x;
    float xv = xn[(size_t)n * DD + t];
    __shared__ float s1[256], s2[256], s3[256];
    s1[t] = xv * le1_w[t];
    s2[t] = xv * le2_w[t];
    s3[t] = xv * le3_w[t];
    __syncthreads();
    for (int d = 128; d > 0; d >>= 1){
        if (t < d){ s1[t] += s1[t+d]; s2[t] += s2[t+d]; s3[t] += s3[t+d]; }
        __syncthreads();
    }
    if (t == 0){
        a_[n] = s1[0] + le1_b[0];
        b_[n] = s2[0];
        c_[n] = s3[0] + le3_b[0];
    }
}

// ---------------- fitness = sigmoid(segsum(a[src]-b[dst]) + c) (one wave per node) --------
__global__ void fitness_kernel(const int* off, const int* eid, const int* e_src,
                               const float* a_, const float* b_, const float* c_,
                               float* fit){
    int wave = threadIdx.x >> 6;
    int lane = threadIdx.x & 63;
    int n = blockIdx.x * 4 + wave;
    int lo = off[n], hi = off[n+1];
    float bn = b_[n];
    float s = 0.f;
    for (int t = lo + lane; t < hi; t += 64){
        int e = eid[t];
        s += a_[esrc(e_src, e)] - bn;
    }
    #pragma unroll
    for (int d = 32; d > 0; d >>= 1) s += __shfl_xor(s, d);
    if (lane == 0){
        float z = s + c_[n];
        fit[n] = 1.f / (1.f + expf(-z));
    }
}

// ---------------- top-k via bitonic sort of (value desc, idx asc) keys ----------------
__global__ void __launch_bounds__(1024) topk_kernel(const float* fit, int* perm, int* colmap,
                                                    float* out_perm){
    __shared__ unsigned long long keys[NN];
    int t = threadIdx.x;
    for (int i = t; i < NN; i += 1024){
        unsigned int u = __float_as_uint(fit[i]);
        u = (u & 0x80000000u) ? ~u : (u | 0x80000000u);  // monotone map
        u = ~u;                                           // descending
        keys[i] = ((unsigned long long)u << 32) | (unsigned int)i;
    }
    __syncthreads();
    for (unsigned int ssize = 2; ssize <= NN; ssize <<= 1){
        for (unsigned int stride = ssize >> 1; stride > 0; stride >>= 1){
            for (int i = t; i < NN / 2; i += 1024){
                unsigned int idx = 2u * i - (i & (stride - 1u));
                unsigned int par = idx + stride;
                bool asc = ((idx & ssize) == 0u);
                unsigned long long a = keys[idx], b = keys[par];
                if ((a > b) == asc){ keys[idx] = b; keys[par] = a; }
            }
            __syncthreads();
        }
    }
    for (int i = t; i < KK; i += 1024){
        int node = (int)(keys[i] & 0xFFFFFFFFull);
        perm[i] = node;
        colmap[node] = i;
        out_perm[i] = (float)node;
    }
}

// ---------------- x_out = xn[perm] * fitness[perm] ----------------
__global__ void xout_kernel(const float* xn, const float* fit, const int* perm, float* x_out){
    int r = blockIdx.x, d = threadIdx.x;
    int p = perm[r];
    x_out[(size_t)r * DD + d] = xn[(size_t)p * DD + d] * fit[p];
}

// ---------------- colc[e] = colmap[dst(e)] ----------------
__global__ void colc_kernel(const int* e_dst, const int* colmap, int* colc){
    int e = blockIdx.x * blockDim.x + threadIdx.x;
    if (e < NE) colc[e] = colmap[edst(e_dst, e)];
}

// ---------------- T[i,:] = sum over out-edges e=(i,j): w_e * Sp[j,:]  (row in LDS) -------
__global__ void spgemm1_kernel(const int* e_dst, const float* ew,
                               const int* off_src, const int* eid_src,
                               const int* colc, const float* sc, float* T){
    __shared__ float row[KK];
    __shared__ int   jlo_[SEGCAP];
    __shared__ int   jhi_[SEGCAP];
    __shared__ float w_[SEGCAP];
    int i = blockIdx.x;
    for (int c = threadIdx.x; c < KK; c += 256) row[c] = 0.f;
    int lo = off_src[i], hi = off_src[i+1];
    int L = hi - lo;
    int Ls = (L <= SEGCAP) ? L : SEGCAP;
    for (int t = threadIdx.x; t < Ls; t += 256){
        int e = eid_src[lo + t];
        int j = edst(e_dst, e);
        jlo_[t] = off_src[j];
        jhi_[t] = off_src[j+1];
        w_[t]   = (e < E0S) ? ew[e] : 1.0f;
    }
    __syncthreads();
    int wave = threadIdx.x >> 6, lane = threadIdx.x & 63;
    for (int t = wave; t < Ls; t += 4){
        float w1 = w_[t];
        for (int u = jlo_[t] + lane; u < jhi_[t]; u += 64){
            int f = eid_src[u];
            int c = colc[f];
            if (c >= 0) atomicAdd(&row[c], w1 * sc[f]);
        }
    }
    for (int t = Ls + wave; t < L; t += 4){   // overflow fallback
        int e = eid_src[lo + t];
        int j = edst(e_dst, e);
        float w1 = (e < E0S) ? ew[e] : 1.0f;
        int jlo = off_src[j], jhi = off_src[j+1];
        for (int u = jlo + lane; u < jhi; u += 64){
            int f = eid_src[u];
            int c = colc[f];
            if (c >= 0) atomicAdd(&row[c], w1 * sc[f]);
        }
    }
    __syncthreads();
    float* Trow = T + (size_t)i * KK;
    for (int c = threadIdx.x; c < KK; c += 256) Trow[c] = row[c];
}

// ---------------- A_c[r, chunk] = sum over in-edges e of perm[r]: sc[e] * T[src(e), chunk] ----
// grid: (KK, 4) blocks; each block handles 512 columns (2 per thread), staged segment in LDS.
#define NCH 4
#define CHW (KK / NCH)   // 512
__global__ void spgemm2_kernel(const int* perm, const int* off_dst, const int* eid_dst,
                               const int* e_src, const float* sc, const float* T, float* Ac){
    __shared__ int   is_[SEGCAP];
    __shared__ float ss_[SEGCAP];
    int r  = blockIdx.x;
    int ch = blockIdx.y;
    int node = perm[r];
    int lo = off_dst[node], hi = off_dst[node+1];
    int L = hi - lo;
    int Ls = (L <= SEGCAP) ? L : SEGCAP;
    for (int t = threadIdx.x; t < Ls; t += 256){
        int e = eid_dst[lo + t];
        is_[t] = esrc(e_src, e);
        ss_[t] = sc[e];
    }
    __syncthreads();
    int c0 = ch * CHW + threadIdx.x;   // columns c0 and c0+256
    float acc0 = 0.f, acc1 = 0.f;
    int t = 0;
    for (; t + 3 < Ls; t += 4){
        const float* T0 = T + (size_t)is_[t]   * KK + c0;
        const float* T1 = T + (size_t)is_[t+1] * KK + c0;
        const float* T2 = T + (size_t)is_[t+2] * KK + c0;
        const float* T3 = T + (size_t)is_[t+3] * KK + c0;
        float a0 = T0[0], a1 = T0[256];
        float b0 = T1[0], b1 = T1[256];
        float d0 = T2[0], d1 = T2[256];
        float e0 = T3[0], e1 = T3[256];
        float s0 = ss_[t], s1 = ss_[t+1], s2 = ss_[t+2], s3 = ss_[t+3];
        acc0 = fmaf(s0, a0, acc0); acc1 = fmaf(s0, a1, acc1);
        acc0 = fmaf(s1, b0, acc0); acc1 = fmaf(s1, b1, acc1);
        acc0 = fmaf(s2, d0, acc0); acc1 = fmaf(s2, d1, acc1);
        acc0 = fmaf(s3, e0, acc0); acc1 = fmaf(s3, e1, acc1);
    }
    for (; t < Ls; ++t){
        const float* T0 = T + (size_t)is_[t] * KK + c0;
        acc0 = fmaf(ss_[t], T0[0],   acc0);
        acc1 = fmaf(ss_[t], T0[256], acc1);
    }
    for (t = Ls; t < L; ++t){            // overflow fallback
        int e = eid_dst[lo + t];
        int i = esrc(e_src, e);
        float s = sc[e];
        const float* T0 = T + (size_t)i * KK + c0;
        acc0 = fmaf(s, T0[0],   acc0);
        acc1 = fmaf(s, T0[256], acc1);
    }
    float* rowp = Ac + (size_t)r * KK;
    rowp[c0]       = (c0 == r)       ? 0.f : acc0;
    rowp[c0 + 256] = (c0 + 256 == r) ? 0.f : acc1;
}

// ---------------- fallback: edge-pair outer products with global atomics ----------------
__global__ void ac_kernel(const int* e_src, const int* e_dst, const float* ew,
                          const int* off_src, const int* eid_src,
                          const int* colc, const float* sc, float* Ac){
    int e1 = blockIdx.x * blockDim.x + threadIdx.x;
    if (e1 >= NE) return;
    int i = (e1 < E0S) ? e_src[e1] : e1 - E0S;
    int j = (e1 < E0S) ? e_dst[e1] : e1 - E0S;
    float w1 = (e1 < E0S) ? ew[e1] : 1.0f;
    int ilo = off_src[i], ihi = off_src[i+1];
    int jlo = off_src[j], jhi = off_src[j+1];
    for (int ta = ilo; ta < ihi; ++ta){
        int ea = eid_src[ta];
        int ca = colc[ea];
        if (ca < 0) continue;
        float va = sc[ea] * w1;
        float* rowp = Ac + (size_t)ca * KK;
        for (int tb = jlo; tb < jhi; ++tb){
            int eb = eid_src[tb];
            int cb = colc[eb];
            if (cb < 0) continue;
            atomicAdd(&rowp[cb], va * sc[eb]);
        }
    }
}

// ---------------- zero diagonal of A_c (fallback path) ----------------
__global__ void diag_kernel(float* Ac){
    int r = blockIdx.x * blockDim.x + threadIdx.x;
    if (r < KK) Ac[(size_t)r * KK + r] = 0.f;
}

extern "C" void kernel_launch(void* const* d_in, const int* in_sizes, int n_in,
                              void* d_out, int out_size, void* d_ws, size_t ws_size,
                              hipStream_t stream){
    const float* x     = (const float*)d_in[0];
    const int*   ei    = (const int*)d_in[1];
    const float* ew    = (const float*)d_in[2];
    const float* lin_w = (const float*)d_in[3];
    const float* lin_b = (const float*)d_in[4];
    const float* att_w = (const float*)d_in[5];
    const float* att_b = (const float*)d_in[6];
    const float* le1_w = (const float*)d_in[7];
    const float* le1_b = (const float*)d_in[8];
    const float* le2_w = (const float*)d_in[9];
    const float* le3_w = (const float*)d_in[10];
    const float* le3_b = (const float*)d_in[11];

    const int* e_src = ei;
    const int* e_dst = ei + E0S;

    float* out    = (float*)d_out;
    float* x_out  = out;                                     // KK*DD
    float* Ac     = out + (size_t)KK * DD;                   // KK*KK
    float* operm  = out + (size_t)KK * DD + (size_t)KK * KK; // KK

    // workspace carve-up (all 4-byte elements)
    char* wp = (char*)d_ws;
    auto alloc_i = [&](size_t n){ int* p = (int*)wp; wp += n * sizeof(int); return p; };
    auto alloc_f = [&](size_t n){ float* p = (float*)wp; wp += n * sizeof(float); return p; };

    int* deg_dst = alloc_i(NN);
    int* deg_src = alloc_i(NN);
    int* off_dst = alloc_i(NN + 1);
    int* off_src = alloc_i(NN + 1);
    int* cur_dst = alloc_i(NN);
    int* cur_src = alloc_i(NN);
    int* eid_dst = alloc_i(NE);
    int* eid_src = alloc_i(NE);
    int* colmap  = alloc_i(NN);
    int* perm    = alloc_i(KK);
    int* colc    = alloc_i(NE);
    float* q_s   = alloc_f(NN);
    float* p_s   = alloc_f(NN);
    float* a_    = alloc_f(NN);
    float* b_    = alloc_f(NN);
    float* c_    = alloc_f(NN);
    float* fit   = alloc_f(NN);
    float* sc    = alloc_f(NE);
    float* x_q   = alloc_f((size_t)NN * DD);
    float* x_ql  = alloc_f((size_t)NN * DD);
    float* xn    = alloc_f((size_t)NN * DD);
    float* T     = alloc_f((size_t)NN * KK);   // 32 MB dense intermediate for A_c
    bool dense_ok = ((size_t)(wp - (char*)d_ws) <= ws_size);
    (void)n_in; (void)in_sizes; (void)out_size;

    const int EB = (NE + 255) / 256;

    init_kernel<<<2048, 256, 0, stream>>>(deg_dst, deg_src, colmap, Ac, dense_ok ? 0 : 1);
    count_kernel<<<EB, 256, 0, stream>>>(e_src, e_dst, deg_dst, deg_src);
    scan_kernel<<<2, 1024, 0, stream>>>(deg_dst, off_dst, cur_dst, deg_src, off_src, cur_src);
    fill_kernel<<<EB, 256, 0, stream>>>(e_src, e_dst, cur_dst, cur_src, eid_dst, eid_src);
    segsort_kernel<<<(2 * NN) / 4, 256, 0, stream>>>(off_dst, eid_dst, off_src, eid_src);
    segmax_kernel<<<NN, 256, 0, stream>>>(x, off_dst, eid_dst, e_src, x_q);
    lin_kernel<<<NN / LROWS, 256, 0, stream>>>(x_q, lin_w, lin_b, x_ql);
    nodedots_kernel<<<NN, 256, 0, stream>>>(x, x_ql, att_w, q_s, p_s);
    softmax_kernel<<<NN / 4, 256, 0, stream>>>(off_dst, eid_dst, e_src, q_s, p_s, att_b, sc);
    xn_kernel<<<NN, 256, 0, stream>>>(x, off_dst, eid_dst, e_src, sc, xn);
    fitdots_kernel<<<NN, 256, 0, stream>>>(xn, le1_w, le1_b, le2_w, le3_w, le3_b, a_, b_, c_);
    fitness_kernel<<<NN / 4, 256, 0, stream>>>(off_dst, eid_dst, e_src, a_, b_, c_, fit);
    topk_kernel<<<1, 1024, 0, stream>>>(fit, perm, colmap, operm);
    xout_kernel<<<KK, 256, 0, stream>>>(xn, fit, perm, x_out);
    colc_kernel<<<EB, 256, 0, stream>>>(e_dst, colmap, colc);
    if (dense_ok){
        spgemm1_kernel<<<NN, 256, 0, stream>>>(e_dst, ew, off_src, eid_src, colc, sc, T);
        spgemm2_kernel<<<dim3(KK, NCH), 256, 0, stream>>>(perm, off_dst, eid_dst, e_src, sc, T, Ac);
    } else {
        ac_kernel<<<EB, 256, 0, stream>>>(e_src, e_dst, ew, off_src, eid_src, colc, sc, Ac);
        diag_kernel<<<(KK + 255) / 256, 256, 0, stream>>>(Ac);
    }
}

// Round 5
// 261.460 us; speedup vs baseline: 11.9632x; 1.0547x over previous
//
#include <hip/hip_runtime.h>
#include <cstdint>
#include <cstddef>
#include <math.h>

#define NN   4096
#define DD   256
#define E0S  131072
#define NE   (E0S + NN)     // 135168 edges incl. self loops
#define KK   2048
#define NEG_SLOPE 0.2f
#define SEGCAP 256          // max segment length staged in LDS

// edge accessors: e < E0S -> from input arrays; else self-loop (e - E0S)
__device__ __forceinline__ int esrc(const int* s, int e){ return e < E0S ? s[e] : e - E0S; }
__device__ __forceinline__ int edst(const int* d, int e){ return e < E0S ? d[e] : e - E0S; }

// ---------------- init: zero degree arrays, colmap=-1, (optionally) zero A_c ------------
__global__ void init_kernel(int* deg_dst, int* deg_src, int* colmap, float* Ac, int zero_ac){
    int i = blockIdx.x * blockDim.x + threadIdx.x;
    int stride = gridDim.x * blockDim.x;
    if (zero_ac){
        for (size_t t = i; t < (size_t)KK * KK; t += stride) Ac[t] = 0.f;
    }
    for (int t = i; t < NN; t += stride){ deg_dst[t] = 0; deg_src[t] = 0; colmap[t] = -1; }
}

// ---------------- degree count ----------------
__global__ void count_kernel(const int* e_src, const int* e_dst, int* deg_dst, int* deg_src){
    int e = blockIdx.x * blockDim.x + threadIdx.x;
    if (e < NE){
        atomicAdd(&deg_dst[edst(e_dst, e)], 1);
        atomicAdd(&deg_src[esrc(e_src, e)], 1);
    }
}

// ---------------- exclusive scan of degrees (one block per array) ----------------
__global__ void __launch_bounds__(1024) scan_kernel(const int* degA, int* offA, int* curA,
                                                    const int* degB, int* offB, int* curB){
    const int* deg = (blockIdx.x == 0) ? degA : degB;
    int* off = (blockIdx.x == 0) ? offA : offB;
    int* cur = (blockIdx.x == 0) ? curA : curB;
    __shared__ int part[1024];
    int t = threadIdx.x;
    int base = t * 4;
    int s0 = deg[base], s1 = deg[base+1], s2 = deg[base+2], s3 = deg[base+3];
    int tot = s0 + s1 + s2 + s3;
    part[t] = tot;
    __syncthreads();
    for (int d = 1; d < 1024; d <<= 1){
        int v = (t >= d) ? part[t - d] : 0;
        __syncthreads();
        part[t] += v;
        __syncthreads();
    }
    int excl = part[t] - tot;
    off[base]   = excl;            cur[base]   = excl;
    off[base+1] = excl + s0;       cur[base+1] = excl + s0;
    off[base+2] = excl + s0 + s1;  cur[base+2] = excl + s0 + s1;
    off[base+3] = excl + s0 + s1 + s2; cur[base+3] = excl + s0 + s1 + s2;
    if (t == 1023) off[NN] = part[1023];
}

// ---------------- CSR fill ----------------
__global__ void fill_kernel(const int* e_src, const int* e_dst, int* cur_dst, int* cur_src,
                            int* eid_dst, int* eid_src){
    int e = blockIdx.x * blockDim.x + threadIdx.x;
    if (e < NE){
        int p = atomicAdd(&cur_dst[edst(e_dst, e)], 1); eid_dst[p] = e;
        int q = atomicAdd(&cur_src[esrc(e_src, e)], 1); eid_src[q] = e;
    }
}

// ---------------- sort each CSR segment ascending (determinism): rank-by-count ----------
__global__ void segsort_kernel(const int* off_dst, int* eid_dst, const int* off_src, int* eid_src){
    __shared__ int buf[4][SEGCAP];
    int wid  = (blockIdx.x * blockDim.x + threadIdx.x) >> 6;   // global wave id in [0, 2*NN)
    int lane = threadIdx.x & 63;
    int w    = threadIdx.x >> 6;
    const int* off; int* eid; int n;
    if (wid < NN){ off = off_dst; eid = eid_dst; n = wid; }
    else         { off = off_src; eid = eid_src; n = wid - NN; }
    int lo = off[n], hi = off[n+1];
    int L = hi - lo;
    int Lc = (L <= SEGCAP) ? L : SEGCAP;
    for (int i = lane; i < Lc; i += 64) buf[w][i] = eid[lo + i];
    __syncthreads();
    if (L <= SEGCAP){
        for (int i = lane; i < L; i += 64){
            int v = buf[w][i];
            int r = 0;
            for (int j = 0; j < L; ++j) r += (buf[w][j] < v);
            eid[lo + r] = v;
        }
    } else if (lane == 0){
        // pathological fallback (never expected at this size)
        for (int i = lo + 1; i < hi; ++i){
            int v = eid[i]; int j = i - 1;
            while (j >= lo && eid[j] > v){ eid[j+1] = eid[j]; --j; }
            eid[j+1] = v;
        }
    }
}

// ---------------- x_q = segment_max(x[src], dst) : one block per node, staged srcs -------
__global__ void segmax_kernel(const float* x, const int* off, const int* eid, const int* e_src,
                              float* x_q){
    __shared__ int is_[SEGCAP];
    int n = blockIdx.x, d = threadIdx.x;
    int lo = off[n], hi = off[n+1];
    int L = hi - lo;
    int Ls = (L <= SEGCAP) ? L : SEGCAP;
    for (int t = d; t < Ls; t += 256) is_[t] = esrc(e_src, eid[lo + t]);
    __syncthreads();
    float m = -INFINITY;
    int t = 0;
    for (; t + 1 < Ls; t += 2){
        float v0 = x[(size_t)is_[t]   * DD + d];
        float v1 = x[(size_t)is_[t+1] * DD + d];
        m = fmaxf(m, fmaxf(v0, v1));
    }
    if (t < Ls) m = fmaxf(m, x[(size_t)is_[t] * DD + d]);
    for (t = Ls; t < L; ++t)  // overflow fallback
        m = fmaxf(m, x[(size_t)esrc(e_src, eid[lo + t]) * DD + d]);
    x_q[(size_t)n * DD + d] = m;
}

// ---------------- x_q_lin = x_q @ lin_w + lin_b ----------------
#define LROWS 8
__global__ void lin_kernel(const float* x_q, const float* w, const float* b, float* out){
    __shared__ float xs[LROWS][DD];
    int col = threadIdx.x;
    int r0 = blockIdx.x * LROWS;
    for (int r = 0; r < LROWS; ++r) xs[r][col] = x_q[(size_t)(r0 + r) * DD + col];
    __syncthreads();
    float acc[LROWS];
    float bc = b[col];
    #pragma unroll
    for (int r = 0; r < LROWS; ++r) acc[r] = bc;
    for (int kk = 0; kk < DD; ++kk){
        float wv = w[(size_t)kk * DD + col];
        #pragma unroll
        for (int r = 0; r < LROWS; ++r) acc[r] = fmaf(xs[r][kk], wv, acc[r]);
    }
    for (int r = 0; r < LROWS; ++r) out[(size_t)(r0 + r) * DD + col] = acc[r];
}

// ---------------- per-node attention dots: q_s = x_q_lin . att_w[0:D], p_s = x . att_w[D:2D] ----
__global__ void nodedots_kernel(const float* x, const float* x_q_lin, const float* att_w,
                                float* q_s, float* p_s){
    int n = blockIdx.x, t = threadIdx.x;
    float v1 = x_q_lin[(size_t)n * DD + t] * att_w[t];
    float v2 = x[(size_t)n * DD + t] * att_w[DD + t];
    __shared__ float s1[256], s2[256];
    s1[t] = v1; s2[t] = v2;
    __syncthreads();
    for (int d = 128; d > 0; d >>= 1){
        if (t < d){ s1[t] += s1[t + d]; s2[t] += s2[t + d]; }
        __syncthreads();
    }
    if (t == 0){ q_s[n] = s1[0]; p_s[n] = s2[0]; }
}

// ---------------- per-dst segment softmax of leaky_relu scores (one wave per node) --------
__global__ void softmax_kernel(const int* off, const int* eid, const int* e_src,
                               const float* q_s, const float* p_s, const float* att_b,
                               float* sc){
    int wave = threadIdx.x >> 6;
    int lane = threadIdx.x & 63;
    int n = blockIdx.x * 4 + wave;
    int lo = off[n], hi = off[n+1];
    float ab = att_b[0];
    float qn = q_s[n];
    float m = -INFINITY;
    for (int t = lo + lane; t < hi; t += 64){
        int e = eid[t];
        float s = qn + p_s[esrc(e_src, e)] + ab;
        s = (s > 0.f) ? s : NEG_SLOPE * s;
        m = fmaxf(m, s);
    }
    #pragma unroll
    for (int d = 32; d > 0; d >>= 1) m = fmaxf(m, __shfl_xor(m, d));
    float sum = 0.f;
    for (int t = lo + lane; t < hi; t += 64){
        int e = eid[t];
        float s = qn + p_s[esrc(e_src, e)] + ab;
        s = (s > 0.f) ? s : NEG_SLOPE * s;
        float ex = expf(s - m);
        sc[e] = ex;
        sum += ex;
    }
    #pragma unroll
    for (int d = 32; d > 0; d >>= 1) sum += __shfl_xor(sum, d);
    float inv = 1.f / sum;
    for (int t = lo + lane; t < hi; t += 64){
        sc[eid[t]] *= inv;
    }
}

// ---------------- xn = segment_sum(x[src] * sc, dst) : one block per node, staged ---------
__global__ void xn_kernel(const float* x, const int* off, const int* eid, const int* e_src,
                          const float* sc, float* xn){
    __shared__ int   is_[SEGCAP];
    __shared__ float ss_[SEGCAP];
    int n = blockIdx.x, d = threadIdx.x;
    int lo = off[n], hi = off[n+1];
    int L = hi - lo;
    int Ls = (L <= SEGCAP) ? L : SEGCAP;
    for (int t = d; t < Ls; t += 256){
        int e = eid[lo + t];
        is_[t] = esrc(e_src, e);
        ss_[t] = sc[e];
    }
    __syncthreads();
    float acc = 0.f;
    int t = 0;
    for (; t + 1 < Ls; t += 2){
        float v0 = x[(size_t)is_[t]   * DD + d];
        float v1 = x[(size_t)is_[t+1] * DD + d];
        acc = fmaf(ss_[t],   v0, acc);   // sequential order preserved
        acc = fmaf(ss_[t+1], v1, acc);
    }
    if (t < Ls) acc = fmaf(ss_[t], x[(size_t)is_[t] * DD + d], acc);
    for (t = Ls; t < L; ++t){            // overflow fallback
        int e = eid[lo + t];
        acc = fmaf(sc[e], x[(size_t)esrc(e_src, e) * DD + d], acc);
    }
    xn[(size_t)n * DD + d] = acc;
}

// ---------------- LEConv dots ----------------
__global__ void fitdots_kernel(const float* xn, const float* le1_w, const float* le1_b,
                               const float* le2_w, const float* le3_w, const float* le3_b,
                               float* a_, float* b_, float* c_){
    int n = blockIdx.x, t = threadIdx.x;
    float xv = xn[(size_t)n * DD + t];
    __shared__ float s1[256], s2[256], s3[256];
    s1[t] = xv * le1_w[t];
    s2[t] = xv * le2_w[t];
    s3[t] = xv * le3_w[t];
    __syncthreads();
    for (int d = 128; d > 0; d >>= 1){
        if (t < d){ s1[t] += s1[t+d]; s2[t] += s2[t+d]; s3[t] += s3[t+d]; }
        __syncthreads();
    }
    if (t == 0){
        a_[n] = s1[0] + le1_b[0];
        b_[n] = s2[0];
        c_[n] = s3[0] + le3_b[0];
    }
}

// ---------------- fitness = sigmoid(segsum(a[src]-b[dst]) + c) (one wave per node) --------
__global__ void fitness_kernel(const int* off, const int* eid, const int* e_src,
                               const float* a_, const float* b_, const float* c_,
                               float* fit){
    int wave = threadIdx.x >> 6;
    int lane = threadIdx.x & 63;
    int n = blockIdx.x * 4 + wave;
    int lo = off[n], hi = off[n+1];
    float bn = b_[n];
    float s = 0.f;
    for (int t = lo + lane; t < hi; t += 64){
        int e = eid[t];
        s += a_[esrc(e_src, e)] - bn;
    }
    #pragma unroll
    for (int d = 32; d > 0; d >>= 1) s += __shfl_xor(s, d);
    if (lane == 0){
        float z = s + c_[n];
        fit[n] = 1.f / (1.f + expf(-z));
    }
}

// ---------------- top-k via bitonic sort of (value desc, idx asc) keys ----------------
__global__ void __launch_bounds__(1024) topk_kernel(const float* fit, int* perm, int* colmap,
                                                    float* out_perm){
    __shared__ unsigned long long keys[NN];
    int t = threadIdx.x;
    for (int i = t; i < NN; i += 1024){
        unsigned int u = __float_as_uint(fit[i]);
        u = (u & 0x80000000u) ? ~u : (u | 0x80000000u);  // monotone map
        u = ~u;                                           // descending
        keys[i] = ((unsigned long long)u << 32) | (unsigned int)i;
    }
    __syncthreads();
    for (unsigned int ssize = 2; ssize <= NN; ssize <<= 1){
        for (unsigned int stride = ssize >> 1; stride > 0; stride >>= 1){
            for (int i = t; i < NN / 2; i += 1024){
                unsigned int idx = 2u * i - (i & (stride - 1u));
                unsigned int par = idx + stride;
                bool asc = ((idx & ssize) == 0u);
                unsigned long long a = keys[idx], b = keys[par];
                if ((a > b) == asc){ keys[idx] = b; keys[par] = a; }
            }
            __syncthreads();
        }
    }
    for (int i = t; i < KK; i += 1024){
        int node = (int)(keys[i] & 0xFFFFFFFFull);
        perm[i] = node;
        colmap[node] = i;
        out_perm[i] = (float)node;
    }
}

// ---------------- x_out = xn[perm] * fitness[perm] ----------------
__global__ void xout_kernel(const float* xn, const float* fit, const int* perm, float* x_out){
    int r = blockIdx.x, d = threadIdx.x;
    int p = perm[r];
    x_out[(size_t)r * DD + d] = xn[(size_t)p * DD + d] * fit[p];
}

// ---------------- colc[e] = colmap[dst(e)] ----------------
__global__ void colc_kernel(const int* e_dst, const int* colmap, int* colc){
    int e = blockIdx.x * blockDim.x + threadIdx.x;
    if (e < NE) colc[e] = colmap[edst(e_dst, e)];
}

// ---------------- T[i,:] = sum over out-edges e=(i,j): w_e * Sp[j,:]  (row in LDS) -------
__global__ void spgemm1_kernel(const int* e_dst, const float* ew,
                               const int* off_src, const int* eid_src,
                               const int* colc, const float* sc, float* T){
    __shared__ float row[KK];
    __shared__ int   jlo_[SEGCAP];
    __shared__ int   jhi_[SEGCAP];
    __shared__ float w_[SEGCAP];
    int i = blockIdx.x;
    for (int c = threadIdx.x; c < KK; c += 256) row[c] = 0.f;
    int lo = off_src[i], hi = off_src[i+1];
    int L = hi - lo;
    int Ls = (L <= SEGCAP) ? L : SEGCAP;
    for (int t = threadIdx.x; t < Ls; t += 256){
        int e = eid_src[lo + t];
        int j = edst(e_dst, e);
        jlo_[t] = off_src[j];
        jhi_[t] = off_src[j+1];
        w_[t]   = (e < E0S) ? ew[e] : 1.0f;
    }
    __syncthreads();
    int wave = threadIdx.x >> 6, lane = threadIdx.x & 63;
    for (int t = wave; t < Ls; t += 4){
        float w1 = w_[t];
        for (int u = jlo_[t] + lane; u < jhi_[t]; u += 64){
            int f = eid_src[u];
            int c = colc[f];
            if (c >= 0) atomicAdd(&row[c], w1 * sc[f]);
        }
    }
    for (int t = Ls + wave; t < L; t += 4){   // overflow fallback
        int e = eid_src[lo + t];
        int j = edst(e_dst, e);
        float w1 = (e < E0S) ? ew[e] : 1.0f;
        int jlo = off_src[j], jhi = off_src[j+1];
        for (int u = jlo + lane; u < jhi; u += 64){
            int f = eid_src[u];
            int c = colc[f];
            if (c >= 0) atomicAdd(&row[c], w1 * sc[f]);
        }
    }
    __syncthreads();
    float* Trow = T + (size_t)i * KK;
    for (int c = threadIdx.x; c < KK; c += 256) Trow[c] = row[c];
}

// ---------------- A_c[r, chunk] = sum over in-edges e of perm[r]: sc[e] * T[src(e), chunk] ----
// grid: dim3(NCH=8, KK). blockIdx.x = column chunk (256 cols, 4 MB T-slice = one XCD L2),
// blockIdx.y = output row. Linear block id = chunk + 8*row -> round-robin XCD dispatch pins
// each chunk to one XCD, so the whole XCD streams the SAME 4 MB slice: L2-resident.
#define NCH 8
#define CHW (KK / NCH)   // 256
__global__ void spgemm2_kernel(const int* perm, const int* off_dst, const int* eid_dst,
                               const int* e_src, const float* sc, const float* T, float* Ac){
    __shared__ int   is_[SEGCAP];
    __shared__ float ss_[SEGCAP];
    int ch = blockIdx.x;
    int r  = blockIdx.y;
    int node = perm[r];
    int lo = off_dst[node], hi = off_dst[node+1];
    int L = hi - lo;
    int Ls = (L <= SEGCAP) ? L : SEGCAP;
    for (int t = threadIdx.x; t < Ls; t += 256){
        int e = eid_dst[lo + t];
        is_[t] = esrc(e_src, e);
        ss_[t] = sc[e];
    }
    __syncthreads();
    int c0 = ch * CHW + threadIdx.x;   // one column per thread
    float acc = 0.f;
    int t = 0;
    for (; t + 3 < Ls; t += 4){
        float a0 = T[(size_t)is_[t]   * KK + c0];
        float a1 = T[(size_t)is_[t+1] * KK + c0];
        float a2 = T[(size_t)is_[t+2] * KK + c0];
        float a3 = T[(size_t)is_[t+3] * KK + c0];
        acc = fmaf(ss_[t],   a0, acc);   // sequential order preserved
        acc = fmaf(ss_[t+1], a1, acc);
        acc = fmaf(ss_[t+2], a2, acc);
        acc = fmaf(ss_[t+3], a3, acc);
    }
    for (; t < Ls; ++t)
        acc = fmaf(ss_[t], T[(size_t)is_[t] * KK + c0], acc);
    for (t = Ls; t < L; ++t){            // overflow fallback
        int e = eid_dst[lo + t];
        acc = fmaf(sc[e], T[(size_t)esrc(e_src, e) * KK + c0], acc);
    }
    Ac[(size_t)r * KK + c0] = (c0 == r) ? 0.f : acc;
}

// ---------------- fallback: edge-pair outer products with global atomics ----------------
__global__ void ac_kernel(const int* e_src, const int* e_dst, const float* ew,
                          const int* off_src, const int* eid_src,
                          const int* colc, const float* sc, float* Ac){
    int e1 = blockIdx.x * blockDim.x + threadIdx.x;
    if (e1 >= NE) return;
    int i = (e1 < E0S) ? e_src[e1] : e1 - E0S;
    int j = (e1 < E0S) ? e_dst[e1] : e1 - E0S;
    float w1 = (e1 < E0S) ? ew[e1] : 1.0f;
    int ilo = off_src[i], ihi = off_src[i+1];
    int jlo = off_src[j], jhi = off_src[j+1];
    for (int ta = ilo; ta < ihi; ++ta){
        int ea = eid_src[ta];
        int ca = colc[ea];
        if (ca < 0) continue;
        float va = sc[ea] * w1;
        float* rowp = Ac + (size_t)ca * KK;
        for (int tb = jlo; tb < jhi; ++tb){
            int eb = eid_src[tb];
            int cb = colc[eb];
            if (cb < 0) continue;
            atomicAdd(&rowp[cb], va * sc[eb]);
        }
    }
}

// ---------------- zero diagonal of A_c (fallback path) ----------------
__global__ void diag_kernel(float* Ac){
    int r = blockIdx.x * blockDim.x + threadIdx.x;
    if (r < KK) Ac[(size_t)r * KK + r] = 0.f;
}

extern "C" void kernel_launch(void* const* d_in, const int* in_sizes, int n_in,
                              void* d_out, int out_size, void* d_ws, size_t ws_size,
                              hipStream_t stream){
    const float* x     = (const float*)d_in[0];
    const int*   ei    = (const int*)d_in[1];
    const float* ew    = (const float*)d_in[2];
    const float* lin_w = (const float*)d_in[3];
    const float* lin_b = (const float*)d_in[4];
    const float* att_w = (const float*)d_in[5];
    const float* att_b = (const float*)d_in[6];
    const float* le1_w = (const float*)d_in[7];
    const float* le1_b = (const float*)d_in[8];
    const float* le2_w = (const float*)d_in[9];
    const float* le3_w = (const float*)d_in[10];
    const float* le3_b = (const float*)d_in[11];

    const int* e_src = ei;
    const int* e_dst = ei + E0S;

    float* out    = (float*)d_out;
    float* x_out  = out;                                     // KK*DD
    float* Ac     = out + (size_t)KK * DD;                   // KK*KK
    float* operm  = out + (size_t)KK * DD + (size_t)KK * KK; // KK

    // workspace carve-up (all 4-byte elements)
    char* wp = (char*)d_ws;
    auto alloc_i = [&](size_t n){ int* p = (int*)wp; wp += n * sizeof(int); return p; };
    auto alloc_f = [&](size_t n){ float* p = (float*)wp; wp += n * sizeof(float); return p; };

    int* deg_dst = alloc_i(NN);
    int* deg_src = alloc_i(NN);
    int* off_dst = alloc_i(NN + 1);
    int* off_src = alloc_i(NN + 1);
    int* cur_dst = alloc_i(NN);
    int* cur_src = alloc_i(NN);
    int* eid_dst = alloc_i(NE);
    int* eid_src = alloc_i(NE);
    int* colmap  = alloc_i(NN);
    int* perm    = alloc_i(KK);
    int* colc    = alloc_i(NE);
    float* q_s   = alloc_f(NN);
    float* p_s   = alloc_f(NN);
    float* a_    = alloc_f(NN);
    float* b_    = alloc_f(NN);
    float* c_    = alloc_f(NN);
    float* fit   = alloc_f(NN);
    float* sc    = alloc_f(NE);
    float* x_q   = alloc_f((size_t)NN * DD);
    float* x_ql  = alloc_f((size_t)NN * DD);
    float* xn    = alloc_f((size_t)NN * DD);
    float* T     = alloc_f((size_t)NN * KK);   // 32 MB dense intermediate for A_c
    bool dense_ok = ((size_t)(wp - (char*)d_ws) <= ws_size);
    (void)n_in; (void)in_sizes; (void)out_size;

    const int EB = (NE + 255) / 256;

    init_kernel<<<2048, 256, 0, stream>>>(deg_dst, deg_src, colmap, Ac, dense_ok ? 0 : 1);
    count_kernel<<<EB, 256, 0, stream>>>(e_src, e_dst, deg_dst, deg_src);
    scan_kernel<<<2, 1024, 0, stream>>>(deg_dst, off_dst, cur_dst, deg_src, off_src, cur_src);
    fill_kernel<<<EB, 256, 0, stream>>>(e_src, e_dst, cur_dst, cur_src, eid_dst, eid_src);
    segsort_kernel<<<(2 * NN) / 4, 256, 0, stream>>>(off_dst, eid_dst, off_src, eid_src);
    segmax_kernel<<<NN, 256, 0, stream>>>(x, off_dst, eid_dst, e_src, x_q);
    lin_kernel<<<NN / LROWS, 256, 0, stream>>>(x_q, lin_w, lin_b, x_ql);
    nodedots_kernel<<<NN, 256, 0, stream>>>(x, x_ql, att_w, q_s, p_s);
    softmax_kernel<<<NN / 4, 256, 0, stream>>>(off_dst, eid_dst, e_src, q_s, p_s, att_b, sc);
    xn_kernel<<<NN, 256, 0, stream>>>(x, off_dst, eid_dst, e_src, sc, xn);
    fitdots_kernel<<<NN, 256, 0, stream>>>(xn, le1_w, le1_b, le2_w, le3_w, le3_b, a_, b_, c_);
    fitness_kernel<<<NN / 4, 256, 0, stream>>>(off_dst, eid_dst, e_src, a_, b_, c_, fit);
    topk_kernel<<<1, 1024, 0, stream>>>(fit, perm, colmap, operm);
    xout_kernel<<<KK, 256, 0, stream>>>(xn, fit, perm, x_out);
    colc_kernel<<<EB, 256, 0, stream>>>(e_dst, colmap, colc);
    if (dense_ok){
        spgemm1_kernel<<<NN, 256, 0, stream>>>(e_dst, ew, off_src, eid_src, colc, sc, T);
        spgemm2_kernel<<<dim3(NCH, KK), 256, 0, stream>>>(perm, off_dst, eid_dst, e_src, sc, T, Ac);
    } else {
        ac_kernel<<<EB, 256, 0, stream>>>(e_src, e_dst, ew, off_src, eid_src, colc, sc, Ac);
        diag_kernel<<<(KK + 255) / 256, 256, 0, stream>>>(Ac);
    }
}

// Round 6
// 243.116 us; speedup vs baseline: 12.8659x; 1.0755x over previous
//
#include <hip/hip_runtime.h>
#include <cstdint>
#include <cstddef>
#include <math.h>

#define NN   4096
#define DD   256
#define E0S  131072
#define NE   (E0S + NN)     // 135168 edges incl. self loops
#define KK   2048
#define NEG_SLOPE 0.2f
#define SEGCAP 256          // max segment length staged in LDS

// edge accessors: e < E0S -> from input arrays; else self-loop (e - E0S)
__device__ __forceinline__ int esrc(const int* s, int e){ return e < E0S ? s[e] : e - E0S; }
__device__ __forceinline__ int edst(const int* d, int e){ return e < E0S ? d[e] : e - E0S; }

// ---------------- init: zero degree arrays, colmap=-1, (optionally) zero A_c ------------
__global__ void init_kernel(int* deg_dst, int* deg_src, int* colmap, float* Ac, int zero_ac){
    int i = blockIdx.x * blockDim.x + threadIdx.x;
    int stride = gridDim.x * blockDim.x;
    if (zero_ac){
        for (size_t t = i; t < (size_t)KK * KK; t += stride) Ac[t] = 0.f;
    }
    for (int t = i; t < NN; t += stride){ deg_dst[t] = 0; deg_src[t] = 0; colmap[t] = -1; }
}

// ---------------- degree count ----------------
__global__ void count_kernel(const int* e_src, const int* e_dst, int* deg_dst, int* deg_src){
    int e = blockIdx.x * blockDim.x + threadIdx.x;
    if (e < NE){
        atomicAdd(&deg_dst[edst(e_dst, e)], 1);
        atomicAdd(&deg_src[esrc(e_src, e)], 1);
    }
}

// ---------------- exclusive scan of degrees (one block per array) ----------------
__global__ void __launch_bounds__(1024) scan_kernel(const int* degA, int* offA, int* curA,
                                                    const int* degB, int* offB, int* curB){
    const int* deg = (blockIdx.x == 0) ? degA : degB;
    int* off = (blockIdx.x == 0) ? offA : offB;
    int* cur = (blockIdx.x == 0) ? curA : curB;
    __shared__ int part[1024];
    int t = threadIdx.x;
    int base = t * 4;
    int s0 = deg[base], s1 = deg[base+1], s2 = deg[base+2], s3 = deg[base+3];
    int tot = s0 + s1 + s2 + s3;
    part[t] = tot;
    __syncthreads();
    for (int d = 1; d < 1024; d <<= 1){
        int v = (t >= d) ? part[t - d] : 0;
        __syncthreads();
        part[t] += v;
        __syncthreads();
    }
    int excl = part[t] - tot;
    off[base]   = excl;            cur[base]   = excl;
    off[base+1] = excl + s0;       cur[base+1] = excl + s0;
    off[base+2] = excl + s0 + s1;  cur[base+2] = excl + s0 + s1;
    off[base+3] = excl + s0 + s1 + s2; cur[base+3] = excl + s0 + s1 + s2;
    if (t == 1023) off[NN] = part[1023];
}

// ---------------- CSR fill ----------------
__global__ void fill_kernel(const int* e_src, const int* e_dst, int* cur_dst, int* cur_src,
                            int* eid_dst, int* eid_src){
    int e = blockIdx.x * blockDim.x + threadIdx.x;
    if (e < NE){
        int p = atomicAdd(&cur_dst[edst(e_dst, e)], 1); eid_dst[p] = e;
        int q = atomicAdd(&cur_src[esrc(e_src, e)], 1); eid_src[q] = e;
    }
}

// ---------------- sort each CSR segment ascending (determinism): rank-by-count ----------
__global__ void segsort_kernel(const int* off_dst, int* eid_dst, const int* off_src, int* eid_src){
    __shared__ int buf[4][SEGCAP];
    int wid  = (blockIdx.x * blockDim.x + threadIdx.x) >> 6;   // global wave id in [0, 2*NN)
    int lane = threadIdx.x & 63;
    int w    = threadIdx.x >> 6;
    const int* off; int* eid; int n;
    if (wid < NN){ off = off_dst; eid = eid_dst; n = wid; }
    else         { off = off_src; eid = eid_src; n = wid - NN; }
    int lo = off[n], hi = off[n+1];
    int L = hi - lo;
    int Lc = (L <= SEGCAP) ? L : SEGCAP;
    for (int i = lane; i < Lc; i += 64) buf[w][i] = eid[lo + i];
    __syncthreads();
    if (L <= SEGCAP){
        for (int i = lane; i < L; i += 64){
            int v = buf[w][i];
            int r = 0;
            for (int j = 0; j < L; ++j) r += (buf[w][j] < v);
            eid[lo + r] = v;
        }
    } else if (lane == 0){
        // pathological fallback (never expected at this size)
        for (int i = lo + 1; i < hi; ++i){
            int v = eid[i]; int j = i - 1;
            while (j >= lo && eid[j] > v){ eid[j+1] = eid[j]; --j; }
            eid[j+1] = v;
        }
    }
}

// ---------------- isd[u] = src node of dst-CSR position u (contiguous) ----------------
__global__ void prepdst_kernel(const int* eid_dst, const int* e_src, int* isd){
    int u = blockIdx.x * blockDim.x + threadIdx.x;
    if (u < NE) isd[u] = esrc(e_src, eid_dst[u]);
}

// ---------------- x_q = segment_max(x[src], dst) : one block per node, staged srcs -------
__global__ void segmax_kernel(const float* x, const int* off, const int* isd, float* x_q){
    __shared__ int is_[SEGCAP];
    int n = blockIdx.x, d = threadIdx.x;
    int lo = off[n], hi = off[n+1];
    int L = hi - lo;
    int Ls = (L <= SEGCAP) ? L : SEGCAP;
    for (int t = d; t < Ls; t += 256) is_[t] = isd[lo + t];
    __syncthreads();
    float m = -INFINITY;
    int t = 0;
    for (; t + 1 < Ls; t += 2){
        float v0 = x[(size_t)is_[t]   * DD + d];
        float v1 = x[(size_t)is_[t+1] * DD + d];
        m = fmaxf(m, fmaxf(v0, v1));
    }
    if (t < Ls) m = fmaxf(m, x[(size_t)is_[t] * DD + d]);
    for (t = Ls; t < L; ++t)  // overflow fallback
        m = fmaxf(m, x[(size_t)isd[lo + t] * DD + d]);
    x_q[(size_t)n * DD + d] = m;
}

// ---------------- x_q_lin = x_q @ lin_w + lin_b ----------------
#define LROWS 8
__global__ void lin_kernel(const float* x_q, const float* w, const float* b, float* out){
    __shared__ float xs[LROWS][DD];
    int col = threadIdx.x;
    int r0 = blockIdx.x * LROWS;
    for (int r = 0; r < LROWS; ++r) xs[r][col] = x_q[(size_t)(r0 + r) * DD + col];
    __syncthreads();
    float acc[LROWS];
    float bc = b[col];
    #pragma unroll
    for (int r = 0; r < LROWS; ++r) acc[r] = bc;
    for (int kk = 0; kk < DD; ++kk){
        float wv = w[(size_t)kk * DD + col];
        #pragma unroll
        for (int r = 0; r < LROWS; ++r) acc[r] = fmaf(xs[r][kk], wv, acc[r]);
    }
    for (int r = 0; r < LROWS; ++r) out[(size_t)(r0 + r) * DD + col] = acc[r];
}

// ---------------- per-node attention dots: q_s = x_q_lin . att_w[0:D], p_s = x . att_w[D:2D] ----
__global__ void nodedots_kernel(const float* x, const float* x_q_lin, const float* att_w,
                                float* q_s, float* p_s){
    int n = blockIdx.x, t = threadIdx.x;
    float v1 = x_q_lin[(size_t)n * DD + t] * att_w[t];
    float v2 = x[(size_t)n * DD + t] * att_w[DD + t];
    __shared__ float s1[256], s2[256];
    s1[t] = v1; s2[t] = v2;
    __syncthreads();
    for (int d = 128; d > 0; d >>= 1){
        if (t < d){ s1[t] += s1[t + d]; s2[t] += s2[t + d]; }
        __syncthreads();
    }
    if (t == 0){ q_s[n] = s1[0]; p_s[n] = s2[0]; }
}

// ---------------- per-dst segment softmax (one wave per node); writes sc (edge-indexed)
// ---------------- and ssd (dst-position-indexed, contiguous) --------------------------
__global__ void softmax_kernel(const int* off, const int* eid, const int* isd,
                               const float* q_s, const float* p_s, const float* att_b,
                               float* sc, float* ssd){
    int wave = threadIdx.x >> 6;
    int lane = threadIdx.x & 63;
    int n = blockIdx.x * 4 + wave;
    int lo = off[n], hi = off[n+1];
    float ab = att_b[0];
    float qn = q_s[n];
    float m = -INFINITY;
    for (int t = lo + lane; t < hi; t += 64){
        float s = qn + p_s[isd[t]] + ab;
        s = (s > 0.f) ? s : NEG_SLOPE * s;
        m = fmaxf(m, s);
    }
    #pragma unroll
    for (int d = 32; d > 0; d >>= 1) m = fmaxf(m, __shfl_xor(m, d));
    float sum = 0.f;
    for (int t = lo + lane; t < hi; t += 64){
        float s = qn + p_s[isd[t]] + ab;
        s = (s > 0.f) ? s : NEG_SLOPE * s;
        float ex = expf(s - m);
        ssd[t] = ex;
        sum += ex;
    }
    #pragma unroll
    for (int d = 32; d > 0; d >>= 1) sum += __shfl_xor(sum, d);
    float inv = 1.f / sum;
    for (int t = lo + lane; t < hi; t += 64){
        float v = ssd[t] * inv;
        ssd[t] = v;
        sc[eid[t]] = v;       // edge-indexed copy (needed by src-side prep)
    }
}

// ---------------- xn = segment_sum(x[src]*ssd, dst) fused with LEConv dots ---------------
__global__ void xnfit_kernel(const float* x, const int* off, const int* isd, const float* ssd,
                             const float* le1_w, const float* le1_b, const float* le2_w,
                             const float* le3_w, const float* le3_b,
                             float* xn, float* a_, float* b_, float* c_){
    __shared__ int   is_[SEGCAP];
    __shared__ float ss_[SEGCAP];
    __shared__ float s1[256], s2[256], s3[256];
    int n = blockIdx.x, d = threadIdx.x;
    int lo = off[n], hi = off[n+1];
    int L = hi - lo;
    int Ls = (L <= SEGCAP) ? L : SEGCAP;
    for (int t = d; t < Ls; t += 256){
        is_[t] = isd[lo + t];
        ss_[t] = ssd[lo + t];
    }
    __syncthreads();
    float acc = 0.f;
    int t = 0;
    for (; t + 1 < Ls; t += 2){
        float v0 = x[(size_t)is_[t]   * DD + d];
        float v1 = x[(size_t)is_[t+1] * DD + d];
        acc = fmaf(ss_[t],   v0, acc);   // sequential order preserved
        acc = fmaf(ss_[t+1], v1, acc);
    }
    if (t < Ls) acc = fmaf(ss_[t], x[(size_t)is_[t] * DD + d], acc);
    for (t = Ls; t < L; ++t)             // overflow fallback
        acc = fmaf(ssd[lo + t], x[(size_t)isd[lo + t] * DD + d], acc);
    xn[(size_t)n * DD + d] = acc;
    // fused LEConv dots (same tree reduction as before -> identical numerics)
    s1[d] = acc * le1_w[d];
    s2[d] = acc * le2_w[d];
    s3[d] = acc * le3_w[d];
    __syncthreads();
    for (int dd = 128; dd > 0; dd >>= 1){
        if (d < dd){ s1[d] += s1[d+dd]; s2[d] += s2[d+dd]; s3[d] += s3[d+dd]; }
        __syncthreads();
    }
    if (d == 0){
        a_[n] = s1[0] + le1_b[0];
        b_[n] = s2[0];
        c_[n] = s3[0] + le3_b[0];
    }
}

// ---------------- fitness = sigmoid(segsum(a[src]-b[dst]) + c) (one wave per node) --------
__global__ void fitness_kernel(const int* off, const int* isd,
                               const float* a_, const float* b_, const float* c_,
                               float* fit){
    int wave = threadIdx.x >> 6;
    int lane = threadIdx.x & 63;
    int n = blockIdx.x * 4 + wave;
    int lo = off[n], hi = off[n+1];
    float bn = b_[n];
    float s = 0.f;
    for (int t = lo + lane; t < hi; t += 64){
        s += a_[isd[t]] - bn;
    }
    #pragma unroll
    for (int d = 32; d > 0; d >>= 1) s += __shfl_xor(s, d);
    if (lane == 0){
        float z = s + c_[n];
        fit[n] = 1.f / (1.f + expf(-z));
    }
}

// ---------------- top-k via bitonic sort of (value desc, idx asc) keys ----------------
__global__ void __launch_bounds__(1024) topk_kernel(const float* fit, int* perm, int* colmap,
                                                    float* out_perm){
    __shared__ unsigned long long keys[NN];
    int t = threadIdx.x;
    for (int i = t; i < NN; i += 1024){
        unsigned int u = __float_as_uint(fit[i]);
        u = (u & 0x80000000u) ? ~u : (u | 0x80000000u);  // monotone map
        u = ~u;                                           // descending
        keys[i] = ((unsigned long long)u << 32) | (unsigned int)i;
    }
    __syncthreads();
    for (unsigned int ssize = 2; ssize <= NN; ssize <<= 1){
        for (unsigned int stride = ssize >> 1; stride > 0; stride >>= 1){
            for (int i = t; i < NN / 2; i += 1024){
                unsigned int idx = 2u * i - (i & (stride - 1u));
                unsigned int par = idx + stride;
                bool asc = ((idx & ssize) == 0u);
                unsigned long long a = keys[idx], b = keys[par];
                if ((a > b) == asc){ keys[idx] = b; keys[par] = a; }
            }
            __syncthreads();
        }
    }
    for (int i = t; i < KK; i += 1024){
        int node = (int)(keys[i] & 0xFFFFFFFFull);
        perm[i] = node;
        colmap[node] = i;
        out_perm[i] = (float)node;
    }
}

// ---------------- x_out = xn[perm] * fitness[perm] ----------------
__global__ void xout_kernel(const float* xn, const float* fit, const int* perm, float* x_out){
    int r = blockIdx.x, d = threadIdx.x;
    int p = perm[r];
    x_out[(size_t)r * DD + d] = xn[(size_t)p * DD + d] * fit[p];
}

// ---------------- colc[e] = colmap[dst(e)] ----------------
__global__ void colc_kernel(const int* e_dst, const int* colmap, int* colc){
    int e = blockIdx.x * blockDim.x + threadIdx.x;
    if (e < NE) colc[e] = colmap[edst(e_dst, e)];
}

// ---------------- cp[u], sp[u] = colc / sc at src-CSR position u (contiguous) ------------
__global__ void prepsrc_kernel(const int* eid_src, const int* colc, const float* sc,
                               int* cp, float* sp){
    int u = blockIdx.x * blockDim.x + threadIdx.x;
    if (u < NE){
        int f = eid_src[u];
        cp[u] = colc[f];
        sp[u] = sc[f];
    }
}

// ---------------- T[i,:] = sum over out-edges e=(i,j): w_e * Sp[j,:]  (row in LDS) -------
__global__ void spgemm1_kernel(const int* e_dst, const float* ew,
                               const int* off_src, const int* eid_src,
                               const int* cp, const float* sp, float* T){
    __shared__ float row[KK];
    __shared__ int   jlo_[SEGCAP];
    __shared__ int   jhi_[SEGCAP];
    __shared__ float w_[SEGCAP];
    int i = blockIdx.x;
    for (int c = threadIdx.x; c < KK; c += 256) row[c] = 0.f;
    int lo = off_src[i], hi = off_src[i+1];
    int L = hi - lo;
    int Ls = (L <= SEGCAP) ? L : SEGCAP;
    for (int t = threadIdx.x; t < Ls; t += 256){
        int e = eid_src[lo + t];
        int j = edst(e_dst, e);
        jlo_[t] = off_src[j];
        jhi_[t] = off_src[j+1];
        w_[t]   = (e < E0S) ? ew[e] : 1.0f;
    }
    __syncthreads();
    int wave = threadIdx.x >> 6, lane = threadIdx.x & 63;
    for (int t = wave; t < Ls; t += 4){
        float w1 = w_[t];
        for (int u = jlo_[t] + lane; u < jhi_[t]; u += 64){
            int c = cp[u];                       // contiguous stream
            if (c >= 0) atomicAdd(&row[c], w1 * sp[u]);
        }
    }
    for (int t = Ls + wave; t < L; t += 4){   // overflow fallback
        int e = eid_src[lo + t];
        int j = edst(e_dst, e);
        float w1 = (e < E0S) ? ew[e] : 1.0f;
        int jlo = off_src[j], jhi = off_src[j+1];
        for (int u = jlo + lane; u < jhi; u += 64){
            int c = cp[u];
            if (c >= 0) atomicAdd(&row[c], w1 * sp[u]);
        }
    }
    __syncthreads();
    float* Trow = T + (size_t)i * KK;
    for (int c = threadIdx.x; c < KK; c += 256) Trow[c] = row[c];
}

// ---------------- A_c[r, chunk] = sum over dst-positions of perm[r]: ssd * T[isd, chunk] ----
// 16 chunks of 128 cols (2 MB T-slice << 4 MB XCD L2). grid dim3(8, 2048), 256 thr:
// chunk = bx + 8*(by>>10)  -> linear id % 8 = bx pins chunk's slice to one XCD;
// the y-order processes chunks 0..7 first, then 8..15 (one 2 MB slice per XCD at a time).
// Each block: 2 rows (tid<128 -> r0, else r1), 1 col/thread. Nontemporal Ac store.
__global__ void spgemm2_kernel(const int* perm, const int* off_dst,
                               const int* isd, const float* ssd,
                               const float* T, float* Ac){
    __shared__ int   is_[2][SEGCAP];
    __shared__ float ss_[2][SEGCAP];
    int bx = blockIdx.x;              // 0..7
    int by = blockIdx.y;              // 0..2047
    int half = by >> 10;              // 0 or 1
    int rr   = by & 1023;
    int sub  = threadIdx.x >> 7;      // 0 or 1 (row within block)
    int lane = threadIdx.x & 127;
    int r = 2 * rr + sub;
    int chunk = bx + 8 * half;
    int c0 = chunk * 128 + lane;
    int node = perm[r];
    int lo = off_dst[node], hi = off_dst[node+1];
    int L = hi - lo;
    int Ls = (L <= SEGCAP) ? L : SEGCAP;
    for (int t = lane; t < Ls; t += 128){
        is_[sub][t] = isd[lo + t];
        ss_[sub][t] = ssd[lo + t];
    }
    __syncthreads();
    float acc = 0.f;
    int t = 0;
    for (; t + 3 < Ls; t += 4){
        float a0 = T[(size_t)is_[sub][t]   * KK + c0];
        float a1 = T[(size_t)is_[sub][t+1] * KK + c0];
        float a2 = T[(size_t)is_[sub][t+2] * KK + c0];
        float a3 = T[(size_t)is_[sub][t+3] * KK + c0];
        acc = fmaf(ss_[sub][t],   a0, acc);   // sequential order preserved
        acc = fmaf(ss_[sub][t+1], a1, acc);
        acc = fmaf(ss_[sub][t+2], a2, acc);
        acc = fmaf(ss_[sub][t+3], a3, acc);
    }
    for (; t < Ls; ++t)
        acc = fmaf(ss_[sub][t], T[(size_t)is_[sub][t] * KK + c0], acc);
    for (t = Ls; t < L; ++t)             // overflow fallback
        acc = fmaf(ssd[lo + t], T[(size_t)isd[lo + t] * KK + c0], acc);
    float v = (c0 == r) ? 0.f : acc;
    __builtin_nontemporal_store(v, &Ac[(size_t)r * KK + c0]);
}

// ---------------- fallback: edge-pair outer products with global atomics ----------------
__global__ void ac_kernel(const int* e_src, const int* e_dst, const float* ew,
                          const int* off_src, const int* eid_src,
                          const int* colc, const float* sc, float* Ac){
    int e1 = blockIdx.x * blockDim.x + threadIdx.x;
    if (e1 >= NE) return;
    int i = (e1 < E0S) ? e_src[e1] : e1 - E0S;
    int j = (e1 < E0S) ? e_dst[e1] : e1 - E0S;
    float w1 = (e1 < E0S) ? ew[e1] : 1.0f;
    int ilo = off_src[i], ihi = off_src[i+1];
    int jlo = off_src[j], jhi = off_src[j+1];
    for (int ta = ilo; ta < ihi; ++ta){
        int ea = eid_src[ta];
        int ca = colc[ea];
        if (ca < 0) continue;
        float va = sc[ea] * w1;
        float* rowp = Ac + (size_t)ca * KK;
        for (int tb = jlo; tb < jhi; ++tb){
            int eb = eid_src[tb];
            int cb = colc[eb];
            if (cb < 0) continue;
            atomicAdd(&rowp[cb], va * sc[eb]);
        }
    }
}

// ---------------- zero diagonal of A_c (fallback path) ----------------
__global__ void diag_kernel(float* Ac){
    int r = blockIdx.x * blockDim.x + threadIdx.x;
    if (r < KK) Ac[(size_t)r * KK + r] = 0.f;
}

extern "C" void kernel_launch(void* const* d_in, const int* in_sizes, int n_in,
                              void* d_out, int out_size, void* d_ws, size_t ws_size,
                              hipStream_t stream){
    const float* x     = (const float*)d_in[0];
    const int*   ei    = (const int*)d_in[1];
    const float* ew    = (const float*)d_in[2];
    const float* lin_w = (const float*)d_in[3];
    const float* lin_b = (const float*)d_in[4];
    const float* att_w = (const float*)d_in[5];
    const float* att_b = (const float*)d_in[6];
    const float* le1_w = (const float*)d_in[7];
    const float* le1_b = (const float*)d_in[8];
    const float* le2_w = (const float*)d_in[9];
    const float* le3_w = (const float*)d_in[10];
    const float* le3_b = (const float*)d_in[11];

    const int* e_src = ei;
    const int* e_dst = ei + E0S;

    float* out    = (float*)d_out;
    float* x_out  = out;                                     // KK*DD
    float* Ac     = out + (size_t)KK * DD;                   // KK*KK
    float* operm  = out + (size_t)KK * DD + (size_t)KK * KK; // KK

    // workspace carve-up (all 4-byte elements)
    char* wp = (char*)d_ws;
    auto alloc_i = [&](size_t n){ int* p = (int*)wp; wp += n * sizeof(int); return p; };
    auto alloc_f = [&](size_t n){ float* p = (float*)wp; wp += n * sizeof(float); return p; };

    int* deg_dst = alloc_i(NN);
    int* deg_src = alloc_i(NN);
    int* off_dst = alloc_i(NN + 1);
    int* off_src = alloc_i(NN + 1);
    int* cur_dst = alloc_i(NN);
    int* cur_src = alloc_i(NN);
    int* eid_dst = alloc_i(NE);
    int* eid_src = alloc_i(NE);
    int* colmap  = alloc_i(NN);
    int* perm    = alloc_i(KK);
    int* colc    = alloc_i(NE);
    int* isd     = alloc_i(NE);    // src node per dst-CSR position
    int* cp      = alloc_i(NE);    // colc per src-CSR position
    float* sp    = alloc_f(NE);    // sc per src-CSR position
    float* ssd   = alloc_f(NE);    // softmax score per dst-CSR position
    float* q_s   = alloc_f(NN);
    float* p_s   = alloc_f(NN);
    float* a_    = alloc_f(NN);
    float* b_    = alloc_f(NN);
    float* c_    = alloc_f(NN);
    float* fit   = alloc_f(NN);
    float* sc    = alloc_f(NE);
    float* x_q   = alloc_f((size_t)NN * DD);
    float* x_ql  = alloc_f((size_t)NN * DD);
    float* xn    = alloc_f((size_t)NN * DD);
    float* T     = alloc_f((size_t)NN * KK);   // 32 MB dense intermediate for A_c
    bool dense_ok = ((size_t)(wp - (char*)d_ws) <= ws_size);
    (void)n_in; (void)in_sizes; (void)out_size;

    const int EB = (NE + 255) / 256;

    init_kernel<<<2048, 256, 0, stream>>>(deg_dst, deg_src, colmap, Ac, dense_ok ? 0 : 1);
    count_kernel<<<EB, 256, 0, stream>>>(e_src, e_dst, deg_dst, deg_src);
    scan_kernel<<<2, 1024, 0, stream>>>(deg_dst, off_dst, cur_dst, deg_src, off_src, cur_src);
    fill_kernel<<<EB, 256, 0, stream>>>(e_src, e_dst, cur_dst, cur_src, eid_dst, eid_src);
    segsort_kernel<<<(2 * NN) / 4, 256, 0, stream>>>(off_dst, eid_dst, off_src, eid_src);
    prepdst_kernel<<<EB, 256, 0, stream>>>(eid_dst, e_src, isd);
    segmax_kernel<<<NN, 256, 0, stream>>>(x, off_dst, isd, x_q);
    lin_kernel<<<NN / LROWS, 256, 0, stream>>>(x_q, lin_w, lin_b, x_ql);
    nodedots_kernel<<<NN, 256, 0, stream>>>(x, x_ql, att_w, q_s, p_s);
    softmax_kernel<<<NN / 4, 256, 0, stream>>>(off_dst, eid_dst, isd, q_s, p_s, att_b, sc, ssd);
    xnfit_kernel<<<NN, 256, 0, stream>>>(x, off_dst, isd, ssd, le1_w, le1_b, le2_w, le3_w, le3_b,
                                         xn, a_, b_, c_);
    fitness_kernel<<<NN / 4, 256, 0, stream>>>(off_dst, isd, a_, b_, c_, fit);
    topk_kernel<<<1, 1024, 0, stream>>>(fit, perm, colmap, operm);
    xout_kernel<<<KK, 256, 0, stream>>>(xn, fit, perm, x_out);
    colc_kernel<<<EB, 256, 0, stream>>>(e_dst, colmap, colc);
    if (dense_ok){
        prepsrc_kernel<<<EB, 256, 0, stream>>>(eid_src, colc, sc, cp, sp);
        spgemm1_kernel<<<NN, 256, 0, stream>>>(e_dst, ew, off_src, eid_src, cp, sp, T);
        spgemm2_kernel<<<dim3(8, KK), 256, 0, stream>>>(perm, off_dst, isd, ssd, T, Ac);
    } else {
        ac_kernel<<<EB, 256, 0, stream>>>(e_src, e_dst, ew, off_src, eid_src, colc, sc, Ac);
        diag_kernel<<<(KK + 255) / 256, 256, 0, stream>>>(Ac);
    }
}

// Round 8
// 228.432 us; speedup vs baseline: 13.6930x; 1.0643x over previous
//
#include <hip/hip_runtime.h>
#include <cstdint>
#include <cstddef>
#include <math.h>

#define NN   4096
#define DD   256
#define E0S  131072
#define NE   (E0S + NN)     // 135168 edges incl. self loops
#define KK   2048
#define NEG_SLOPE 0.2f
#define SEGCAP 256          // max segment length staged in LDS

typedef float floatx4 __attribute__((ext_vector_type(4)));   // clang-native vec4

// edge accessors: e < E0S -> from input arrays; else self-loop (e - E0S)
__device__ __forceinline__ int esrc(const int* s, int e){ return e < E0S ? s[e] : e - E0S; }
__device__ __forceinline__ int edst(const int* d, int e){ return e < E0S ? d[e] : e - E0S; }

// ---------------- init: zero degree arrays, colmap=-1, (optionally) zero A_c ------------
__global__ void init_kernel(int* deg_dst, int* deg_src, int* colmap, float* Ac, int zero_ac){
    int i = blockIdx.x * blockDim.x + threadIdx.x;
    int stride = gridDim.x * blockDim.x;
    if (zero_ac){
        for (size_t t = i; t < (size_t)KK * KK; t += stride) Ac[t] = 0.f;
    }
    for (int t = i; t < NN; t += stride){ deg_dst[t] = 0; deg_src[t] = 0; colmap[t] = -1; }
}

// ---------------- degree count ----------------
__global__ void count_kernel(const int* e_src, const int* e_dst, int* deg_dst, int* deg_src){
    int e = blockIdx.x * blockDim.x + threadIdx.x;
    if (e < NE){
        atomicAdd(&deg_dst[edst(e_dst, e)], 1);
        atomicAdd(&deg_src[esrc(e_src, e)], 1);
    }
}

// ---------------- exclusive scan of degrees (one block per array) ----------------
__global__ void __launch_bounds__(1024) scan_kernel(const int* degA, int* offA, int* curA,
                                                    const int* degB, int* offB, int* curB){
    const int* deg = (blockIdx.x == 0) ? degA : degB;
    int* off = (blockIdx.x == 0) ? offA : offB;
    int* cur = (blockIdx.x == 0) ? curA : curB;
    __shared__ int part[1024];
    int t = threadIdx.x;
    int base = t * 4;
    int s0 = deg[base], s1 = deg[base+1], s2 = deg[base+2], s3 = deg[base+3];
    int tot = s0 + s1 + s2 + s3;
    part[t] = tot;
    __syncthreads();
    for (int d = 1; d < 1024; d <<= 1){
        int v = (t >= d) ? part[t - d] : 0;
        __syncthreads();
        part[t] += v;
        __syncthreads();
    }
    int excl = part[t] - tot;
    off[base]   = excl;            cur[base]   = excl;
    off[base+1] = excl + s0;       cur[base+1] = excl + s0;
    off[base+2] = excl + s0 + s1;  cur[base+2] = excl + s0 + s1;
    off[base+3] = excl + s0 + s1 + s2; cur[base+3] = excl + s0 + s1 + s2;
    if (t == 1023) off[NN] = part[1023];
}

// ---------------- CSR fill ----------------
__global__ void fill_kernel(const int* e_src, const int* e_dst, int* cur_dst, int* cur_src,
                            int* eid_dst, int* eid_src){
    int e = blockIdx.x * blockDim.x + threadIdx.x;
    if (e < NE){
        int p = atomicAdd(&cur_dst[edst(e_dst, e)], 1); eid_dst[p] = e;
        int q = atomicAdd(&cur_src[esrc(e_src, e)], 1); eid_src[q] = e;
    }
}

// ---------------- sort each CSR segment ascending (determinism): rank-by-count ----------
// also emits isd[u] = src node at dst-CSR position u (fused former prepdst kernel)
__global__ void segsort_kernel(const int* off_dst, int* eid_dst, const int* off_src, int* eid_src,
                               const int* e_src, int* isd){
    __shared__ int buf[4][SEGCAP];
    int wid  = (blockIdx.x * blockDim.x + threadIdx.x) >> 6;   // global wave id in [0, 2*NN)
    int lane = threadIdx.x & 63;
    int w    = threadIdx.x >> 6;
    const int* off; int* eid; int n; bool isdst;
    if (wid < NN){ off = off_dst; eid = eid_dst; n = wid; isdst = true; }
    else         { off = off_src; eid = eid_src; n = wid - NN; isdst = false; }
    int lo = off[n], hi = off[n+1];
    int L = hi - lo;
    int Lc = (L <= SEGCAP) ? L : SEGCAP;
    for (int i = lane; i < Lc; i += 64) buf[w][i] = eid[lo + i];
    __syncthreads();
    if (L <= SEGCAP){
        for (int i = lane; i < L; i += 64){
            int v = buf[w][i];
            int r = 0;
            for (int j = 0; j < L; ++j) r += (buf[w][j] < v);
            eid[lo + r] = v;
            if (isdst) isd[lo + r] = esrc(e_src, v);
        }
    } else if (lane == 0){
        // pathological fallback (never expected at this size)
        for (int i = lo + 1; i < hi; ++i){
            int v = eid[i]; int j = i - 1;
            while (j >= lo && eid[j] > v){ eid[j+1] = eid[j]; --j; }
            eid[j+1] = v;
        }
        if (isdst) for (int i = lo; i < hi; ++i) isd[i] = esrc(e_src, eid[i]);
    }
}

// ---------------- x_q = segment_max(x[src], dst) : one block per node, staged srcs -------
__global__ void segmax_kernel(const float* x, const int* off, const int* isd, float* x_q){
    __shared__ int is_[SEGCAP];
    int n = blockIdx.x, d = threadIdx.x;
    int lo = off[n], hi = off[n+1];
    int L = hi - lo;
    int Ls = (L <= SEGCAP) ? L : SEGCAP;
    for (int t = d; t < Ls; t += 256) is_[t] = isd[lo + t];
    __syncthreads();
    float m = -INFINITY;
    int t = 0;
    for (; t + 1 < Ls; t += 2){
        float v0 = x[(size_t)is_[t]   * DD + d];
        float v1 = x[(size_t)is_[t+1] * DD + d];
        m = fmaxf(m, fmaxf(v0, v1));
    }
    if (t < Ls) m = fmaxf(m, x[(size_t)is_[t] * DD + d]);
    for (t = Ls; t < L; ++t)  // overflow fallback
        m = fmaxf(m, x[(size_t)isd[lo + t] * DD + d]);
    x_q[(size_t)n * DD + d] = m;
}

// ---------------- x_q_lin = x_q @ lin_w + lin_b ----------------
#define LROWS 8
__global__ void lin_kernel(const float* x_q, const float* w, const float* b, float* out){
    __shared__ float xs[LROWS][DD];
    int col = threadIdx.x;
    int r0 = blockIdx.x * LROWS;
    for (int r = 0; r < LROWS; ++r) xs[r][col] = x_q[(size_t)(r0 + r) * DD + col];
    __syncthreads();
    float acc[LROWS];
    float bc = b[col];
    #pragma unroll
    for (int r = 0; r < LROWS; ++r) acc[r] = bc;
    for (int kk = 0; kk < DD; ++kk){
        float wv = w[(size_t)kk * DD + col];
        #pragma unroll
        for (int r = 0; r < LROWS; ++r) acc[r] = fmaf(xs[r][kk], wv, acc[r]);
    }
    for (int r = 0; r < LROWS; ++r) out[(size_t)(r0 + r) * DD + col] = acc[r];
}

// ---------------- per-node attention dots: q_s = x_q_lin . att_w[0:D], p_s = x . att_w[D:2D] ----
__global__ void nodedots_kernel(const float* x, const float* x_q_lin, const float* att_w,
                                float* q_s, float* p_s){
    int n = blockIdx.x, t = threadIdx.x;
    float v1 = x_q_lin[(size_t)n * DD + t] * att_w[t];
    float v2 = x[(size_t)n * DD + t] * att_w[DD + t];
    __shared__ float s1[256], s2[256];
    s1[t] = v1; s2[t] = v2;
    __syncthreads();
    for (int d = 128; d > 0; d >>= 1){
        if (t < d){ s1[t] += s1[t + d]; s2[t] += s2[t + d]; }
        __syncthreads();
    }
    if (t == 0){ q_s[n] = s1[0]; p_s[n] = s2[0]; }
}

// ---------------- per-dst segment softmax (one wave per node); writes sc (edge-indexed)
// ---------------- and ssd (dst-position-indexed, contiguous) --------------------------
__global__ void softmax_kernel(const int* off, const int* eid, const int* isd,
                               const float* q_s, const float* p_s, const float* att_b,
                               float* sc, float* ssd){
    int wave = threadIdx.x >> 6;
    int lane = threadIdx.x & 63;
    int n = blockIdx.x * 4 + wave;
    int lo = off[n], hi = off[n+1];
    float ab = att_b[0];
    float qn = q_s[n];
    float m = -INFINITY;
    for (int t = lo + lane; t < hi; t += 64){
        float s = qn + p_s[isd[t]] + ab;
        s = (s > 0.f) ? s : NEG_SLOPE * s;
        m = fmaxf(m, s);
    }
    #pragma unroll
    for (int d = 32; d > 0; d >>= 1) m = fmaxf(m, __shfl_xor(m, d));
    float sum = 0.f;
    for (int t = lo + lane; t < hi; t += 64){
        float s = qn + p_s[isd[t]] + ab;
        s = (s > 0.f) ? s : NEG_SLOPE * s;
        float ex = expf(s - m);
        ssd[t] = ex;
        sum += ex;
    }
    #pragma unroll
    for (int d = 32; d > 0; d >>= 1) sum += __shfl_xor(sum, d);
    float inv = 1.f / sum;
    for (int t = lo + lane; t < hi; t += 64){
        float v = ssd[t] * inv;
        ssd[t] = v;
        sc[eid[t]] = v;       // edge-indexed copy (needed by src-side prep)
    }
}

// ---------------- xn = segment_sum(x[src]*ssd, dst) fused with LEConv dots ---------------
__global__ void xnfit_kernel(const float* x, const int* off, const int* isd, const float* ssd,
                             const float* le1_w, const float* le1_b, const float* le2_w,
                             const float* le3_w, const float* le3_b,
                             float* xn, float* a_, float* b_, float* c_){
    __shared__ int   is_[SEGCAP];
    __shared__ float ss_[SEGCAP];
    __shared__ float s1[256], s2[256], s3[256];
    int n = blockIdx.x, d = threadIdx.x;
    int lo = off[n], hi = off[n+1];
    int L = hi - lo;
    int Ls = (L <= SEGCAP) ? L : SEGCAP;
    for (int t = d; t < Ls; t += 256){
        is_[t] = isd[lo + t];
        ss_[t] = ssd[lo + t];
    }
    __syncthreads();
    float acc = 0.f;
    int t = 0;
    for (; t + 1 < Ls; t += 2){
        float v0 = x[(size_t)is_[t]   * DD + d];
        float v1 = x[(size_t)is_[t+1] * DD + d];
        acc = fmaf(ss_[t],   v0, acc);   // sequential order preserved
        acc = fmaf(ss_[t+1], v1, acc);
    }
    if (t < Ls) acc = fmaf(ss_[t], x[(size_t)is_[t] * DD + d], acc);
    for (t = Ls; t < L; ++t)             // overflow fallback
        acc = fmaf(ssd[lo + t], x[(size_t)isd[lo + t] * DD + d], acc);
    xn[(size_t)n * DD + d] = acc;
    // fused LEConv dots (same tree reduction as before -> identical numerics)
    s1[d] = acc * le1_w[d];
    s2[d] = acc * le2_w[d];
    s3[d] = acc * le3_w[d];
    __syncthreads();
    for (int dd = 128; dd > 0; dd >>= 1){
        if (d < dd){ s1[d] += s1[d+dd]; s2[d] += s2[d+dd]; s3[d] += s3[d+dd]; }
        __syncthreads();
    }
    if (d == 0){
        a_[n] = s1[0] + le1_b[0];
        b_[n] = s2[0];
        c_[n] = s3[0] + le3_b[0];
    }
}

// ---------------- fitness = sigmoid(segsum(a[src]-b[dst]) + c) (one wave per node) --------
__global__ void fitness_kernel(const int* off, const int* isd,
                               const float* a_, const float* b_, const float* c_,
                               float* fit){
    int wave = threadIdx.x >> 6;
    int lane = threadIdx.x & 63;
    int n = blockIdx.x * 4 + wave;
    int lo = off[n], hi = off[n+1];
    float bn = b_[n];
    float s = 0.f;
    for (int t = lo + lane; t < hi; t += 64){
        s += a_[isd[t]] - bn;
    }
    #pragma unroll
    for (int d = 32; d > 0; d >>= 1) s += __shfl_xor(s, d);
    if (lane == 0){
        float z = s + c_[n];
        fit[n] = 1.f / (1.f + expf(-z));
    }
}

// ---------------- top-k via bitonic sort of (value desc, idx asc) keys ----------------
__global__ void __launch_bounds__(1024) topk_kernel(const float* fit, int* perm, int* colmap,
                                                    float* out_perm){
    __shared__ unsigned long long keys[NN];
    int t = threadIdx.x;
    for (int i = t; i < NN; i += 1024){
        unsigned int u = __float_as_uint(fit[i]);
        u = (u & 0x80000000u) ? ~u : (u | 0x80000000u);  // monotone map
        u = ~u;                                           // descending
        keys[i] = ((unsigned long long)u << 32) | (unsigned int)i;
    }
    __syncthreads();
    for (unsigned int ssize = 2; ssize <= NN; ssize <<= 1){
        for (unsigned int stride = ssize >> 1; stride > 0; stride >>= 1){
            for (int i = t; i < NN / 2; i += 1024){
                unsigned int idx = 2u * i - (i & (stride - 1u));
                unsigned int par = idx + stride;
                bool asc = ((idx & ssize) == 0u);
                unsigned long long a = keys[idx], b = keys[par];
                if ((a > b) == asc){ keys[idx] = b; keys[par] = a; }
            }
            __syncthreads();
        }
    }
    for (int i = t; i < KK; i += 1024){
        int node = (int)(keys[i] & 0xFFFFFFFFull);
        perm[i] = node;
        colmap[node] = i;
        out_perm[i] = (float)node;
    }
}

// ---------------- x_out = xn[perm] * fitness[perm] ----------------
__global__ void xout_kernel(const float* xn, const float* fit, const int* perm, float* x_out){
    int r = blockIdx.x, d = threadIdx.x;
    int p = perm[r];
    x_out[(size_t)r * DD + d] = xn[(size_t)p * DD + d] * fit[p];
}

// ---------------- cp[u], sp[u] = colmap[dst] / sc at src-CSR position u (contiguous) -----
__global__ void prepsrc_kernel(const int* eid_src, const int* e_dst, const int* colmap,
                               const float* sc, int* cp, float* sp){
    int u = blockIdx.x * blockDim.x + threadIdx.x;
    if (u < NE){
        int f = eid_src[u];
        cp[u] = colmap[edst(e_dst, f)];
        sp[u] = sc[f];
    }
}

// ---------------- T[i,:] = sum over out-edges e=(i,j): w_e * Sp[j,:]  (row in LDS) -------
__global__ void spgemm1_kernel(const int* e_dst, const float* ew,
                               const int* off_src, const int* eid_src,
                               const int* cp, const float* sp, float* T){
    __shared__ float row[KK];
    __shared__ int   jlo_[SEGCAP];
    __shared__ int   jhi_[SEGCAP];
    __shared__ float w_[SEGCAP];
    int i = blockIdx.x;
    for (int c = threadIdx.x; c < KK; c += 256) row[c] = 0.f;
    int lo = off_src[i], hi = off_src[i+1];
    int L = hi - lo;
    int Ls = (L <= SEGCAP) ? L : SEGCAP;
    for (int t = threadIdx.x; t < Ls; t += 256){
        int e = eid_src[lo + t];
        int j = edst(e_dst, e);
        jlo_[t] = off_src[j];
        jhi_[t] = off_src[j+1];
        w_[t]   = (e < E0S) ? ew[e] : 1.0f;
    }
    __syncthreads();
    int wave = threadIdx.x >> 6, lane = threadIdx.x & 63;
    for (int t = wave; t < Ls; t += 4){
        float w1 = w_[t];
        for (int u = jlo_[t] + lane; u < jhi_[t]; u += 64){
            int c = cp[u];                       // contiguous stream
            if (c >= 0) atomicAdd(&row[c], w1 * sp[u]);
        }
    }
    for (int t = Ls + wave; t < L; t += 4){   // overflow fallback
        int e = eid_src[lo + t];
        int j = edst(e_dst, e);
        float w1 = (e < E0S) ? ew[e] : 1.0f;
        int jlo = off_src[j], jhi = off_src[j+1];
        for (int u = jlo + lane; u < jhi; u += 64){
            int c = cp[u];
            if (c >= 0) atomicAdd(&row[c], w1 * sp[u]);
        }
    }
    __syncthreads();
    float* Trow = T + (size_t)i * KK;
    for (int c = threadIdx.x; c < KK; c += 256) Trow[c] = row[c];
}

// ---------------- A_c[r, chunk] = sum over dst-positions of perm[r]: ssd * T[isd, chunk] ----
// 16 chunks of 128 cols (2 MB T-slice << 4 MB XCD L2). grid dim3(8, 512), 256 thr:
// chunk = bx + 8*(by>>8) -> linear id % 8 = bx pins each chunk's slice to one XCD;
// y-order processes chunks 0..7 first, then 8..15 (one 2 MB slice per XCD at a time).
// Each block: 8 rows (32 lanes/row), floatx4 (4 cols) per thread. Nontemporal Ac store.
__global__ void spgemm2_kernel(const int* perm, const int* off_dst,
                               const int* isd, const float* ssd,
                               const float* T, float* Ac){
    __shared__ int   is_[8][SEGCAP];
    __shared__ float ss_[8][SEGCAP];
    int bx = blockIdx.x;              // 0..7
    int by = blockIdx.y;              // 0..511
    int half = by >> 8;               // 0 or 1
    int rr   = by & 255;              // 0..255
    int sub  = threadIdx.x >> 5;      // 0..7 (row within block)
    int lane = threadIdx.x & 31;      // 0..31
    int r = rr * 8 + sub;
    int chunk = bx + 8 * half;        // 0..15
    int c0 = chunk * 128 + lane * 4;  // 4 consecutive columns per thread
    int node = perm[r];
    int lo = off_dst[node], hi = off_dst[node+1];
    int L = hi - lo;
    int Ls = (L <= SEGCAP) ? L : SEGCAP;
    for (int t = lane; t < Ls; t += 32){
        is_[sub][t] = isd[lo + t];
        ss_[sub][t] = ssd[lo + t];
    }
    __syncthreads();
    floatx4 acc = {0.f, 0.f, 0.f, 0.f};
    int t = 0;
    for (; t + 1 < Ls; t += 2){
        floatx4 a = *(const floatx4*)&T[(size_t)is_[sub][t]   * KK + c0];
        floatx4 b = *(const floatx4*)&T[(size_t)is_[sub][t+1] * KK + c0];
        float s0 = ss_[sub][t], s1 = ss_[sub][t+1];
        // per-column order is strictly sequential in t -> numerics identical
        acc.x = fmaf(s0, a.x, acc.x); acc.y = fmaf(s0, a.y, acc.y);
        acc.z = fmaf(s0, a.z, acc.z); acc.w = fmaf(s0, a.w, acc.w);
        acc.x = fmaf(s1, b.x, acc.x); acc.y = fmaf(s1, b.y, acc.y);
        acc.z = fmaf(s1, b.z, acc.z); acc.w = fmaf(s1, b.w, acc.w);
    }
    for (; t < Ls; ++t){
        floatx4 a = *(const floatx4*)&T[(size_t)is_[sub][t] * KK + c0];
        float s0 = ss_[sub][t];
        acc.x = fmaf(s0, a.x, acc.x); acc.y = fmaf(s0, a.y, acc.y);
        acc.z = fmaf(s0, a.z, acc.z); acc.w = fmaf(s0, a.w, acc.w);
    }
    for (t = Ls; t < L; ++t){            // overflow fallback
        floatx4 a = *(const floatx4*)&T[(size_t)isd[lo + t] * KK + c0];
        float s0 = ssd[lo + t];
        acc.x = fmaf(s0, a.x, acc.x); acc.y = fmaf(s0, a.y, acc.y);
        acc.z = fmaf(s0, a.z, acc.z); acc.w = fmaf(s0, a.w, acc.w);
    }
    if (r - c0 >= 0 && r - c0 < 4){      // zero the diagonal element
        if (r - c0 == 0) acc.x = 0.f;
        else if (r - c0 == 1) acc.y = 0.f;
        else if (r - c0 == 2) acc.z = 0.f;
        else acc.w = 0.f;
    }
    __builtin_nontemporal_store(acc, (floatx4*)&Ac[(size_t)r * KK + c0]);
}

// ---------------- fallback: edge-pair outer products with global atomics ----------------
__global__ void ac_kernel(const int* e_src, const int* e_dst, const float* ew,
                          const int* off_src,
                          const int* cp, const float* sp, float* Ac){
    int e1 = blockIdx.x * blockDim.x + threadIdx.x;
    if (e1 >= NE) return;
    int i = (e1 < E0S) ? e_src[e1] : e1 - E0S;
    int j = (e1 < E0S) ? e_dst[e1] : e1 - E0S;
    float w1 = (e1 < E0S) ? ew[e1] : 1.0f;
    int ilo = off_src[i], ihi = off_src[i+1];
    int jlo = off_src[j], jhi = off_src[j+1];
    for (int ta = ilo; ta < ihi; ++ta){
        int ca = cp[ta];
        if (ca < 0) continue;
        float va = sp[ta] * w1;
        float* rowp = Ac + (size_t)ca * KK;
        for (int tb = jlo; tb < jhi; ++tb){
            int cb = cp[tb];
            if (cb < 0) continue;
            atomicAdd(&rowp[cb], va * sp[tb]);
        }
    }
}

// ---------------- zero diagonal of A_c (fallback path) ----------------
__global__ void diag_kernel(float* Ac){
    int r = blockIdx.x * blockDim.x + threadIdx.x;
    if (r < KK) Ac[(size_t)r * KK + r] = 0.f;
}

extern "C" void kernel_launch(void* const* d_in, const int* in_sizes, int n_in,
                              void* d_out, int out_size, void* d_ws, size_t ws_size,
                              hipStream_t stream){
    const float* x     = (const float*)d_in[0];
    const int*   ei    = (const int*)d_in[1];
    const float* ew    = (const float*)d_in[2];
    const float* lin_w = (const float*)d_in[3];
    const float* lin_b = (const float*)d_in[4];
    const float* att_w = (const float*)d_in[5];
    const float* att_b = (const float*)d_in[6];
    const float* le1_w = (const float*)d_in[7];
    const float* le1_b = (const float*)d_in[8];
    const float* le2_w = (const float*)d_in[9];
    const float* le3_w = (const float*)d_in[10];
    const float* le3_b = (const float*)d_in[11];

    const int* e_src = ei;
    const int* e_dst = ei + E0S;

    float* out    = (float*)d_out;
    float* x_out  = out;                                     // KK*DD
    float* Ac     = out + (size_t)KK * DD;                   // KK*KK
    float* operm  = out + (size_t)KK * DD + (size_t)KK * KK; // KK

    // workspace carve-up (all 4-byte elements)
    char* wp = (char*)d_ws;
    auto alloc_i = [&](size_t n){ int* p = (int*)wp; wp += n * sizeof(int); return p; };
    auto alloc_f = [&](size_t n){ float* p = (float*)wp; wp += n * sizeof(float); return p; };

    int* deg_dst = alloc_i(NN);
    int* deg_src = alloc_i(NN);
    int* off_dst = alloc_i(NN + 1);
    int* off_src = alloc_i(NN + 1);
    int* cur_dst = alloc_i(NN);
    int* cur_src = alloc_i(NN);
    int* eid_dst = alloc_i(NE);
    int* eid_src = alloc_i(NE);
    int* colmap  = alloc_i(NN);
    int* perm    = alloc_i(KK);
    int* isd     = alloc_i(NE);    // src node per dst-CSR position
    int* cp      = alloc_i(NE);    // colmap[dst] per src-CSR position
    float* sp    = alloc_f(NE);    // sc per src-CSR position
    float* ssd   = alloc_f(NE);    // softmax score per dst-CSR position
    float* q_s   = alloc_f(NN);
    float* p_s   = alloc_f(NN);
    float* a_    = alloc_f(NN);
    float* b_    = alloc_f(NN);
    float* c_    = alloc_f(NN);
    float* fit   = alloc_f(NN);
    float* sc    = alloc_f(NE);
    float* x_q   = alloc_f((size_t)NN * DD);
    float* x_ql  = alloc_f((size_t)NN * DD);
    float* xn    = alloc_f((size_t)NN * DD);
    float* T     = alloc_f((size_t)NN * KK);   // 32 MB dense intermediate for A_c
    bool dense_ok = ((size_t)(wp - (char*)d_ws) <= ws_size);
    (void)n_in; (void)in_sizes; (void)out_size;

    const int EB = (NE + 255) / 256;

    init_kernel<<<2048, 256, 0, stream>>>(deg_dst, deg_src, colmap, Ac, dense_ok ? 0 : 1);
    count_kernel<<<EB, 256, 0, stream>>>(e_src, e_dst, deg_dst, deg_src);
    scan_kernel<<<2, 1024, 0, stream>>>(deg_dst, off_dst, cur_dst, deg_src, off_src, cur_src);
    fill_kernel<<<EB, 256, 0, stream>>>(e_src, e_dst, cur_dst, cur_src, eid_dst, eid_src);
    segsort_kernel<<<(2 * NN) / 4, 256, 0, stream>>>(off_dst, eid_dst, off_src, eid_src, e_src, isd);
    segmax_kernel<<<NN, 256, 0, stream>>>(x, off_dst, isd, x_q);
    lin_kernel<<<NN / LROWS, 256, 0, stream>>>(x_q, lin_w, lin_b, x_ql);
    nodedots_kernel<<<NN, 256, 0, stream>>>(x, x_ql, att_w, q_s, p_s);
    softmax_kernel<<<NN / 4, 256, 0, stream>>>(off_dst, eid_dst, isd, q_s, p_s, att_b, sc, ssd);
    xnfit_kernel<<<NN, 256, 0, stream>>>(x, off_dst, isd, ssd, le1_w, le1_b, le2_w, le3_w, le3_b,
                                         xn, a_, b_, c_);
    fitness_kernel<<<NN / 4, 256, 0, stream>>>(off_dst, isd, a_, b_, c_, fit);
    topk_kernel<<<1, 1024, 0, stream>>>(fit, perm, colmap, operm);
    xout_kernel<<<KK, 256, 0, stream>>>(xn, fit, perm, x_out);
    prepsrc_kernel<<<EB, 256, 0, stream>>>(eid_src, e_dst, colmap, sc, cp, sp);
    if (dense_ok){
        spgemm1_kernel<<<NN, 256, 0, stream>>>(e_dst, ew, off_src, eid_src, cp, sp, T);
        spgemm2_kernel<<<dim3(8, 512), 256, 0, stream>>>(perm, off_dst, isd, ssd, T, Ac);
    } else {
        ac_kernel<<<EB, 256, 0, stream>>>(e_src, e_dst, ew, off_src, cp, sp, Ac);
        diag_kernel<<<(KK + 255) / 256, 256, 0, stream>>>(Ac);
    }
}